// Round 2
// baseline (11636.982 us; speedup 1.0000x reference)
//
#include <hip/hip_runtime.h>
#include <hip/hip_bf16.h>
#include <stdint.h>

#define B_   512
#define H_   1024
#define T_   144
#define NG   4096
#define NOUT 17

typedef __bf16 bf16_t;
typedef __bf16 bf16x8 __attribute__((ext_vector_type(8)));
typedef float  f32x4  __attribute__((ext_vector_type(4)));

__device__ __host__ __forceinline__ int npack(int n) {
  int g = n >> 10, j = n & 1023;
  return ((j >> 4) << 6) + (g << 4) + (j & 15);
}
__device__ __forceinline__ float sigf(float x) { return 1.f / (1.f + __expf(-x)); }
__device__ __forceinline__ float tanhf_(float x) { return 1.f - 2.f / (__expf(2.f * x) + 1.f); }

__device__ __forceinline__ void gload_lds16(const void* g, void* l) {
  __builtin_amdgcn_global_load_lds(
      (__attribute__((address_space(1))) void*)(void*)(uintptr_t)g,
      (__attribute__((address_space(3))) void*)l, 16, 0, 0);
}

// ---------------- prep kernels ----------------

__global__ void k_pack_wA(const float* __restrict__ Whh0, bf16_t* __restrict__ PWA) {
  int idx = blockIdx.x * 256 + threadIdx.x;     // 4096*128
  int n = idx >> 7, kc = idx & 127;
  const float* s = Whh0 + (size_t)n * H_ + kc * 8;
  bf16x8 v;
#pragma unroll
  for (int e = 0; e < 8; ++e) v[e] = (bf16_t)s[e];
  *(bf16x8*)(PWA + (size_t)npack(n) * H_ + kc * 8) = v;
}

__global__ void k_pack_wB(const float* __restrict__ Wih1, const float* __restrict__ Whh1,
                          bf16_t* __restrict__ PWB) {
  int idx = blockIdx.x * 256 + threadIdx.x;     // 4096*256
  int n = idx >> 8, kc = idx & 255;
  int k = kc * 8;
  const float* s = (k < H_) ? (Wih1 + (size_t)n * H_ + k) : (Whh1 + (size_t)n * H_ + (k - H_));
  bf16x8 v;
#pragma unroll
  for (int e = 0; e < 8; ++e) v[e] = (bf16_t)s[e];
  *(bf16x8*)(PWB + (size_t)npack(n) * 2048 + k) = v;
}

// G[c][n] = sum_k ff_W[k][c] * Wih0[n][512+k];  G[32][n] = sum_k ff_b[k]*Wih0[n][512+k]
__global__ void k_G(const float* __restrict__ Wih0, const float* __restrict__ ffW,
                    const float* __restrict__ ffb, float* __restrict__ G) {
  int n = blockIdx.x * 256 + threadIdx.x;       // 4096
  float acc[33];
#pragma unroll
  for (int c = 0; c < 33; ++c) acc[c] = 0.f;
  for (int k = 0; k < 512; ++k) {
    float wv = Wih0[(size_t)n * H_ + 512 + k];
    const float* fr = ffW + (size_t)k * 32;
#pragma unroll
    for (int c = 0; c < 32; ++c) acc[c] += wv * fr[c];
    acc[32] += wv * ffb[k];
  }
  for (int c = 0; c < 33; ++c) G[(size_t)c * NG + n] = acc[c];
}

// CHp[b][n'] = biasA[n] + G[32][n] + sum_c cond[b][c]*G[c][n]
__global__ void k_CHp(const float* __restrict__ cond, const float* __restrict__ G,
                      const float* __restrict__ bih0, const float* __restrict__ bhh0,
                      float* __restrict__ CHp) {
  int idx = blockIdx.x * 256 + threadIdx.x;     // 512*4096
  int b = idx >> 12, n = idx & 4095;
  float acc = bih0[n] + bhh0[n] + G[(size_t)32 * NG + n];
  const float* cb = cond + (size_t)b * 32;
#pragma unroll
  for (int c = 0; c < 32; ++c) acc += cb[c] * G[(size_t)c * NG + n];
  CHp[(size_t)b * NG + npack(n)] = acc;
}

// E16p[a][n'] = sum_{k<511} emb[a][k] * Wih0[n][k]
__global__ void k_E16(const float* __restrict__ emb, const float* __restrict__ Wih0,
                      float* __restrict__ E16p) {
  int idx = blockIdx.x * 256 + threadIdx.x;     // 16*4096
  int a = idx & 15, n = idx >> 4;
  const float* er = emb + (size_t)a * 511;
  const float* wr = Wih0 + (size_t)n * H_;
  float acc = 0.f;
  for (int k = 0; k < 511; ++k) acc += er[k] * wr[k];
  E16p[(size_t)a * NG + npack(n)] = acc;
}

__global__ void k_misc(const float* __restrict__ Wih0, const float* __restrict__ bih,
                       const float* __restrict__ bhh, const float* __restrict__ fcW,
                       bf16_t* __restrict__ fcWp, float* __restrict__ biasBp,
                       float* __restrict__ wcolp) {
  int idx = blockIdx.x * 256 + threadIdx.x;     // 17408
  if (idx < NG) {
    int np = npack(idx);
    biasBp[np] = bih[NG + idx] + bhh[NG + idx];
    wcolp[np]  = Wih0[(size_t)idx * H_ + 511];
  }
  if (idx < 17 * H_) fcWp[idx] = (bf16_t)fcW[idx];
}

__global__ void k_init(const float* __restrict__ h0, const float* __restrict__ c0,
                       bf16_t* __restrict__ h0a, bf16_t* __restrict__ h1a,
                       float* __restrict__ c0s, float* __restrict__ c1s) {
  int idx = blockIdx.x * 256 + threadIdx.x;     // 512*1024
  h0a[idx] = (bf16_t)h0[idx];
  h1a[idx] = (bf16_t)h0[(size_t)B_ * H_ + idx];
  c0s[idx] = c0[idx];
  c1s[idx] = c0[(size_t)B_ * H_ + idx];
}

// ---------------- main persistent kernel ----------------

struct Params {
  const int* acts; const float* durs;
  const bf16_t* PWA; const bf16_t* PWB;
  const float* CHp; const float* E16p; const float* wcolp; const float* biasBp;
  const bf16_t* fcW; const float* fcb;
  bf16_t* h0a; bf16_t* h0b; bf16_t* h1a; bf16_t* h1b;
  float* c0s; float* c1s;
  unsigned* bar; float* out;
};

__device__ __forceinline__ void gbar(unsigned* cnt, unsigned tgt, int tid) {
  __syncthreads();
  if (tid == 0) {
    __hip_atomic_fetch_add(cnt, 1u, __ATOMIC_RELEASE, __HIP_MEMORY_SCOPE_AGENT);
    while (__hip_atomic_load(cnt, __ATOMIC_RELAXED, __HIP_MEMORY_SCOPE_AGENT) < tgt)
      __builtin_amdgcn_s_sleep(2);
    __builtin_amdgcn_fence(__ATOMIC_ACQUIRE, "agent");
  }
  __syncthreads();
}

__device__ __forceinline__ void stage_tileA(const bf16_t* src, int k0, char* ldsA, int tid) {
#pragma unroll
  for (int j = 0; j < 4; ++j) {
    int chunk = j * 256 + tid;                   // 0..1023 -> 128 rows x 8 segs
    int r = chunk >> 3, seg = chunk & 7, sl = seg ^ (r & 7);
    gload_lds16((const char*)(src + (size_t)r * H_ + k0) + sl * 16, ldsA + chunk * 16);
  }
}

__device__ __forceinline__ void stage_tileB(const bf16_t* src, int ldk, int k0, char* ldsB, int tid) {
#pragma unroll
  for (int j = 0; j < 2; ++j) {
    int chunk = j * 256 + tid;                   // 0..511 -> 64 rows x 8 segs
    int c = chunk >> 3, seg = chunk & 7, sl = seg ^ (c & 7);
    gload_lds16((const char*)(src + (size_t)c * ldk + k0) + sl * 16, ldsB + chunk * 16);
  }
}

__device__ __forceinline__ void mfma_tile(f32x4 (&acc)[4][2], const char* ldsA, const char* ldsB,
                                          int w, int jj, int rq) {
#pragma unroll
  for (int s = 0; s < 2; ++s) {
    bf16x8 av[2], bv[4];
#pragma unroll
    for (int rg = 0; rg < 2; ++rg) {
      int row = w * 32 + rg * 16 + jj;
      int kb = ((s * 32 + rq * 8) * 2) ^ ((row & 7) << 4);
      av[rg] = *(const bf16x8*)(ldsA + row * 128 + kb);
    }
#pragma unroll
    for (int g = 0; g < 4; ++g) {
      int c = g * 16 + jj;
      int kb = ((s * 32 + rq * 8) * 2) ^ ((c & 7) << 4);
      bv[g] = *(const bf16x8*)(ldsB + c * 128 + kb);
    }
#pragma unroll
    for (int g = 0; g < 4; ++g)
#pragma unroll
      for (int rg = 0; rg < 2; ++rg)
        acc[g][rg] = __builtin_amdgcn_mfma_f32_16x16x32_bf16(av[rg], bv[g], acc[g][rg], 0, 0, 0);
  }
}

__device__ void predjob(const Params& p, const bf16_t* h1, int tt, int wg, int w, int l, int tid,
                        float* predbuf) {
  for (int j = w; j < 34; j += 4) {
    int bl = (j >= 17) ? 1 : 0;
    int o = j - bl * 17;
    int b = wg * 2 + bl;
    const bf16_t* hr = h1 + (size_t)b * H_ + l * 16;
    const bf16_t* wr = p.fcW + (size_t)o * H_ + l * 16;
    bf16x8 hv0 = *(const bf16x8*)hr, hv1 = *(const bf16x8*)(hr + 8);
    bf16x8 wv0 = *(const bf16x8*)wr, wv1 = *(const bf16x8*)(wr + 8);
    float acc = 0.f;
#pragma unroll
    for (int e = 0; e < 8; ++e) acc += (float)hv0[e] * (float)wv0[e] + (float)hv1[e] * (float)wv1[e];
#pragma unroll
    for (int d = 32; d > 0; d >>= 1) acc += __shfl_xor(acc, d, 64);
    if (l == 0) predbuf[j] = acc + p.fcb[o];
  }
  __syncthreads();
  if (tid < 2) {
    int b = wg * 2 + tid;
    const float* pr = predbuf + tid * 17;
    float m = pr[0];
    for (int o = 1; o < 16; ++o) m = fmaxf(m, pr[o]);
    float s = 0.f;
    for (int o = 0; o < 16; ++o) s += expf(pr[o] - m);
    float lse = m + logf(s);
    float* dst = p.out + ((size_t)b * T_ + tt) * NOUT;
    for (int o = 0; o < 16; ++o) dst[o] = pr[o] - lse;
    float x = pr[16];
    dst[16] = (x > 0.f) ? -log1pf(expf(-x)) : (x - log1pf(expf(x)));
  }
}

__global__ __launch_bounds__(256, 1) void lstm_main(Params p) {
  __shared__ __align__(16) char smem[24576];
  __shared__ float predbuf[34];
  char* ldsA = smem;            // [128][64] bf16, XOR-swizzled rows
  char* ldsB = smem + 16384;    // [64][64]

  const int tid = threadIdx.x;
  const int w = tid >> 6, l = tid & 63;
  const int wg = blockIdx.x;
  const int q = wg >> 3;
  const int mt = q & 3;                       // M-tile 0..3
  const int jt = ((q >> 2) << 3) + (wg & 7);  // j-tile 0..63 (XCD co-located m-tiles)
  const int jj = l & 15;
  const int rq = l >> 4;
  const int jcol = jt * 16 + jj;
  const int npb = jt * 64;

  unsigned target = 0;

  for (int t = 0; t < T_; ++t) {
    const bf16_t* h0p = (t & 1) ? p.h0b : p.h0a;
    bf16_t*       h0n = (t & 1) ? p.h0a : p.h0b;
    const bf16_t* h1p = (t & 1) ? p.h1b : p.h1a;
    bf16_t*       h1n = (t & 1) ? p.h1a : p.h1b;

    // -------- phase 1: gates0 = h0_prev @ Whh0^T (+ precomputed x-terms) --------
    {
      f32x4 acc[4][2];
#pragma unroll
      for (int g = 0; g < 4; ++g)
#pragma unroll
        for (int rg = 0; rg < 2; ++rg) acc[g][rg] = (f32x4){0.f, 0.f, 0.f, 0.f};

      const bf16_t* Abase = h0p + (size_t)mt * 128 * H_;
      const bf16_t* Bbase = p.PWA + (size_t)jt * 64 * H_;
#pragma unroll 1
      for (int ki = 0; ki < 16; ++ki) {
        __syncthreads();
        stage_tileA(Abase, ki * 64, ldsA, tid);
        stage_tileB(Bbase, H_, ki * 64, ldsB, tid);
        __syncthreads();
        mfma_tile(acc, ldsA, ldsB, w, jj, rq);
      }
      // epilogue: fused LSTM cell, layer 0
#pragma unroll
      for (int rg = 0; rg < 2; ++rg) {
#pragma unroll
        for (int qq = 0; qq < 4; ++qq) {
          int b = mt * 128 + w * 32 + rg * 16 + rq * 4 + qq;
          int act = 0; float dur = 0.f;
          if (t > 0) {
            act = p.acts[(size_t)b * T_ + t - 1];
            dur = p.durs[(size_t)b * T_ + t - 1];
          }
          float pre[4];
#pragma unroll
          for (int g = 0; g < 4; ++g) {
            int np = npb + g * 16 + jj;
            pre[g] = acc[g][rg][qq] + p.CHp[(size_t)b * NG + np]
                   + p.E16p[(size_t)act * NG + np] + dur * p.wcolp[np];
          }
          float co = p.c0s[(size_t)b * H_ + jcol];
          float cn = sigf(pre[1]) * co + sigf(pre[0]) * tanhf_(pre[2]);
          float hn = sigf(pre[3]) * tanhf_(cn);
          p.c0s[(size_t)b * H_ + jcol] = cn;
          h0n[(size_t)b * H_ + jcol] = (bf16_t)hn;
        }
      }
      if (t > 0) predjob(p, h1p, t - 1, wg, w, l, tid, predbuf);
      target += 256; gbar(p.bar, target, tid);
    }

    // -------- phase 2: gates1 = [h0_t ; h1_prev] @ [Wih1;Whh1]^T --------
    {
      f32x4 acc[4][2];
#pragma unroll
      for (int g = 0; g < 4; ++g)
#pragma unroll
        for (int rg = 0; rg < 2; ++rg) acc[g][rg] = (f32x4){0.f, 0.f, 0.f, 0.f};

      const bf16_t* A0 = h0n + (size_t)mt * 128 * H_;
      const bf16_t* A1 = h1p + (size_t)mt * 128 * H_;
      const bf16_t* Bbase = p.PWB + (size_t)jt * 64 * 2048;
#pragma unroll 1
      for (int ki = 0; ki < 32; ++ki) {
        __syncthreads();
        if (ki < 16) stage_tileA(A0, ki * 64, ldsA, tid);
        else         stage_tileA(A1, (ki - 16) * 64, ldsA, tid);
        stage_tileB(Bbase, 2048, ki * 64, ldsB, tid);
        __syncthreads();
        mfma_tile(acc, ldsA, ldsB, w, jj, rq);
      }
      // epilogue: fused LSTM cell, layer 1
#pragma unroll
      for (int rg = 0; rg < 2; ++rg) {
#pragma unroll
        for (int qq = 0; qq < 4; ++qq) {
          int b = mt * 128 + w * 32 + rg * 16 + rq * 4 + qq;
          float pre[4];
#pragma unroll
          for (int g = 0; g < 4; ++g) {
            int np = npb + g * 16 + jj;
            pre[g] = acc[g][rg][qq] + p.biasBp[np];
          }
          float co = p.c1s[(size_t)b * H_ + jcol];
          float cn = sigf(pre[1]) * co + sigf(pre[0]) * tanhf_(pre[2]);
          float hn = sigf(pre[3]) * tanhf_(cn);
          p.c1s[(size_t)b * H_ + jcol] = cn;
          h1n[(size_t)b * H_ + jcol] = (bf16_t)hn;
        }
      }
      target += 256; gbar(p.bar, target, tid);
    }
  }
  // final prediction for t = T-1 (T even -> last h1 written to h1a)
  predjob(p, (T_ & 1) ? p.h1b : p.h1a, T_ - 1, wg, w, l, tid, predbuf);
}

// ---------------- launch ----------------

extern "C" void kernel_launch(void* const* d_in, const int* in_sizes, int n_in,
                              void* d_out, int out_size, void* d_ws, size_t ws_size,
                              hipStream_t stream) {
  (void)in_sizes; (void)n_in; (void)out_size; (void)ws_size;
  const float* h0   = (const float*)d_in[1];
  const float* c0   = (const float*)d_in[2];
  const float* cond = (const float*)d_in[3];
  const int*   acts = (const int*)d_in[4];
  const float* durs = (const float*)d_in[5];
  const float* emb  = (const float*)d_in[6];
  const float* ffW  = (const float*)d_in[7];
  const float* ffb  = (const float*)d_in[8];
  const float* Wih  = (const float*)d_in[9];
  const float* Whh  = (const float*)d_in[10];
  const float* bih  = (const float*)d_in[11];
  const float* bhh  = (const float*)d_in[12];
  const float* fcW  = (const float*)d_in[13];
  const float* fcb  = (const float*)d_in[14];

  char* ws = (char*)d_ws;
  size_t off = 0;
  auto alloc = [&](size_t bytes) -> char* {
    char* p0 = ws + off;
    off = (off + bytes + 255) & ~(size_t)255;
    return p0;
  };
  unsigned* bar   = (unsigned*)alloc(256);
  bf16_t* PWA     = (bf16_t*)alloc((size_t)NG * H_ * 2);
  bf16_t* PWB     = (bf16_t*)alloc((size_t)NG * 2048 * 2);
  float*  CHp     = (float*)alloc((size_t)B_ * NG * 4);
  float*  E16p    = (float*)alloc((size_t)16 * NG * 4);
  float*  wcolp   = (float*)alloc((size_t)NG * 4);
  float*  biasBp  = (float*)alloc((size_t)NG * 4);
  float*  G       = (float*)alloc((size_t)33 * NG * 4);
  bf16_t* fcWp    = (bf16_t*)alloc((size_t)17 * H_ * 2);
  bf16_t* h0a     = (bf16_t*)alloc((size_t)B_ * H_ * 2);
  bf16_t* h0b     = (bf16_t*)alloc((size_t)B_ * H_ * 2);
  bf16_t* h1a     = (bf16_t*)alloc((size_t)B_ * H_ * 2);
  bf16_t* h1b     = (bf16_t*)alloc((size_t)B_ * H_ * 2);
  float*  c0s     = (float*)alloc((size_t)B_ * H_ * 4);
  float*  c1s     = (float*)alloc((size_t)B_ * H_ * 4);

  hipMemsetAsync(bar, 0, 256, stream);
  k_pack_wA<<<2048, 256, 0, stream>>>(Whh, PWA);
  k_pack_wB<<<4096, 256, 0, stream>>>(Wih + (size_t)NG * H_, Whh + (size_t)NG * H_, PWB);
  k_G<<<16, 256, 0, stream>>>(Wih, ffW, ffb, G);
  k_CHp<<<8192, 256, 0, stream>>>(cond, G, bih, bhh, CHp);
  k_E16<<<256, 256, 0, stream>>>(emb, Wih, E16p);
  k_misc<<<68, 256, 0, stream>>>(Wih, bih, bhh, fcW, fcWp, biasBp, wcolp);
  k_init<<<2048, 256, 0, stream>>>(h0, c0, h0a, h1a, c0s, c1s);

  Params prm;
  prm.acts = acts; prm.durs = durs;
  prm.PWA = PWA; prm.PWB = PWB;
  prm.CHp = CHp; prm.E16p = E16p; prm.wcolp = wcolp; prm.biasBp = biasBp;
  prm.fcW = fcWp; prm.fcb = fcb;
  prm.h0a = h0a; prm.h0b = h0b; prm.h1a = h1a; prm.h1b = h1b;
  prm.c0s = c0s; prm.c1s = c1s;
  prm.bar = bar; prm.out = (float*)d_out;

  lstm_main<<<dim3(256), dim3(256), 0, stream>>>(prm);
}

// Round 3
// 11578.973 us; speedup vs baseline: 1.0050x; 1.0050x over previous
//
#include <hip/hip_runtime.h>
#include <hip/hip_bf16.h>
#include <stdint.h>

#define B_   512
#define H_   1024
#define T_   144
#define NG   4096
#define NOUT 17

typedef __bf16 bf16_t;
typedef __bf16 bf16x8 __attribute__((ext_vector_type(8)));
typedef float  f32x4  __attribute__((ext_vector_type(4)));

__device__ __host__ __forceinline__ int npack(int n) {
  int g = n >> 10, j = n & 1023;
  return ((j >> 4) << 6) + (g << 4) + (j & 15);
}
__device__ __forceinline__ float sigf(float x) { return 1.f / (1.f + __expf(-x)); }
__device__ __forceinline__ float tanhf_(float x) { return 1.f - 2.f / (__expf(2.f * x) + 1.f); }

__device__ __forceinline__ void gload_lds16(const void* g, void* l) {
  __builtin_amdgcn_global_load_lds(
      (__attribute__((address_space(1))) void*)(void*)(uintptr_t)g,
      (__attribute__((address_space(3))) void*)l, 16, 0, 0);
}

// ---------------- prep kernels ----------------

__global__ void k_pack_wA(const float* __restrict__ Whh0, bf16_t* __restrict__ PWA) {
  int idx = blockIdx.x * 256 + threadIdx.x;     // 4096*128
  int n = idx >> 7, kc = idx & 127;
  const float* s = Whh0 + (size_t)n * H_ + kc * 8;
  bf16x8 v;
#pragma unroll
  for (int e = 0; e < 8; ++e) v[e] = (bf16_t)s[e];
  *(bf16x8*)(PWA + (size_t)npack(n) * H_ + kc * 8) = v;
}

__global__ void k_pack_wB(const float* __restrict__ Wih1, const float* __restrict__ Whh1,
                          bf16_t* __restrict__ PWB) {
  int idx = blockIdx.x * 256 + threadIdx.x;     // 4096*256
  int n = idx >> 8, kc = idx & 255;
  int k = kc * 8;
  const float* s = (k < H_) ? (Wih1 + (size_t)n * H_ + k) : (Whh1 + (size_t)n * H_ + (k - H_));
  bf16x8 v;
#pragma unroll
  for (int e = 0; e < 8; ++e) v[e] = (bf16_t)s[e];
  *(bf16x8*)(PWB + (size_t)npack(n) * 2048 + k) = v;
}

// G[c][n] = sum_k ff_W[k][c] * Wih0[n][512+k];  G[32][n] = sum_k ff_b[k]*Wih0[n][512+k]
__global__ void k_G(const float* __restrict__ Wih0, const float* __restrict__ ffW,
                    const float* __restrict__ ffb, float* __restrict__ G) {
  int n = blockIdx.x * 256 + threadIdx.x;       // 4096
  float acc[33];
#pragma unroll
  for (int c = 0; c < 33; ++c) acc[c] = 0.f;
  for (int k = 0; k < 512; ++k) {
    float wv = Wih0[(size_t)n * H_ + 512 + k];
    const float* fr = ffW + (size_t)k * 32;
#pragma unroll
    for (int c = 0; c < 32; ++c) acc[c] += wv * fr[c];
    acc[32] += wv * ffb[k];
  }
  for (int c = 0; c < 33; ++c) G[(size_t)c * NG + n] = acc[c];
}

// CHp[b][n'] = biasA[n] + G[32][n] + sum_c cond[b][c]*G[c][n]
__global__ void k_CHp(const float* __restrict__ cond, const float* __restrict__ G,
                      const float* __restrict__ bih0, const float* __restrict__ bhh0,
                      float* __restrict__ CHp) {
  int idx = blockIdx.x * 256 + threadIdx.x;     // 512*4096
  int b = idx >> 12, n = idx & 4095;
  float acc = bih0[n] + bhh0[n] + G[(size_t)32 * NG + n];
  const float* cb = cond + (size_t)b * 32;
#pragma unroll
  for (int c = 0; c < 32; ++c) acc += cb[c] * G[(size_t)c * NG + n];
  CHp[(size_t)b * NG + npack(n)] = acc;
}

// E16p[a][n'] = sum_{k<511} emb[a][k] * Wih0[n][k]
__global__ void k_E16(const float* __restrict__ emb, const float* __restrict__ Wih0,
                      float* __restrict__ E16p) {
  int idx = blockIdx.x * 256 + threadIdx.x;     // 16*4096
  int a = idx & 15, n = idx >> 4;
  const float* er = emb + (size_t)a * 511;
  const float* wr = Wih0 + (size_t)n * H_;
  float acc = 0.f;
  for (int k = 0; k < 511; ++k) acc += er[k] * wr[k];
  E16p[(size_t)a * NG + npack(n)] = acc;
}

__global__ void k_misc(const float* __restrict__ Wih0, const float* __restrict__ bih,
                       const float* __restrict__ bhh, const float* __restrict__ fcW,
                       bf16_t* __restrict__ fcWp, float* __restrict__ biasBp,
                       float* __restrict__ wcolp) {
  int idx = blockIdx.x * 256 + threadIdx.x;     // 17408
  if (idx < NG) {
    int np = npack(idx);
    biasBp[np] = bih[NG + idx] + bhh[NG + idx];
    wcolp[np]  = Wih0[(size_t)idx * H_ + 511];
  }
  if (idx < 17 * H_) fcWp[idx] = (bf16_t)fcW[idx];
}

__global__ void k_init(const float* __restrict__ h0, const float* __restrict__ c0,
                       bf16_t* __restrict__ h0a, bf16_t* __restrict__ h1a,
                       float* __restrict__ c0s, float* __restrict__ c1s) {
  int idx = blockIdx.x * 256 + threadIdx.x;     // 512*1024
  h0a[idx] = (bf16_t)h0[idx];
  h1a[idx] = (bf16_t)h0[(size_t)B_ * H_ + idx];
  c0s[idx] = c0[idx];
  c1s[idx] = c0[(size_t)B_ * H_ + idx];
}

// ---------------- main persistent kernel ----------------

struct Params {
  const int* acts; const float* durs;
  const bf16_t* PWA; const bf16_t* PWB;
  const float* CHp; const float* E16p; const float* wcolp; const float* biasBp;
  const bf16_t* fcW; const float* fcb;
  bf16_t* h0a; bf16_t* h0b; bf16_t* h1a; bf16_t* h1b;
  float* c0s; float* c1s;
  unsigned* slots; float* out;
};

// flag-slot grid barrier: each WG store-releases its own padded slot with the
// monotone phase number; every thread polls one slot (read-only, no RMW chain).
__device__ __forceinline__ void gbar(unsigned* slots, unsigned phase, int tid, int wg) {
  __syncthreads();   // all waves' global writes drained (vmcnt 0) before signaling
  if (tid == 0)
    __hip_atomic_store(slots + (size_t)wg * 16, phase, __ATOMIC_RELEASE, __HIP_MEMORY_SCOPE_AGENT);
  while (__hip_atomic_load(slots + (size_t)tid * 16, __ATOMIC_RELAXED, __HIP_MEMORY_SCOPE_AGENT) < phase)
    __builtin_amdgcn_s_sleep(1);
  __builtin_amdgcn_fence(__ATOMIC_ACQUIRE, "agent");
  __syncthreads();
}

__device__ __forceinline__ void stage_tileA(const bf16_t* src, int k0, char* ldsA, int tid) {
#pragma unroll
  for (int j = 0; j < 4; ++j) {
    int chunk = j * 256 + tid;                   // 0..1023 -> 128 rows x 8 segs
    int r = chunk >> 3, seg = chunk & 7, sl = seg ^ (r & 7);
    gload_lds16((const char*)(src + (size_t)r * H_ + k0) + sl * 16, ldsA + chunk * 16);
  }
}

__device__ __forceinline__ void stage_tileB(const bf16_t* src, int ldk, int k0, char* ldsB, int tid) {
#pragma unroll
  for (int j = 0; j < 2; ++j) {
    int chunk = j * 256 + tid;                   // 0..511 -> 64 rows x 8 segs
    int c = chunk >> 3, seg = chunk & 7, sl = seg ^ (c & 7);
    gload_lds16((const char*)(src + (size_t)c * ldk + k0) + sl * 16, ldsB + chunk * 16);
  }
}

__device__ __forceinline__ void mfma_tile(f32x4 (&acc)[4][2], const char* ldsA, const char* ldsB,
                                          int w, int jj, int rq) {
#pragma unroll
  for (int s = 0; s < 2; ++s) {
    bf16x8 av[2], bv[4];
#pragma unroll
    for (int rg = 0; rg < 2; ++rg) {
      int row = w * 32 + rg * 16 + jj;
      int kb = ((s * 32 + rq * 8) * 2) ^ ((row & 7) << 4);
      av[rg] = *(const bf16x8*)(ldsA + row * 128 + kb);
    }
#pragma unroll
    for (int g = 0; g < 4; ++g) {
      int c = g * 16 + jj;
      int kb = ((s * 32 + rq * 8) * 2) ^ ((c & 7) << 4);
      bv[g] = *(const bf16x8*)(ldsB + c * 128 + kb);
    }
#pragma unroll
    for (int g = 0; g < 4; ++g)
#pragma unroll
      for (int rg = 0; rg < 2; ++rg)
        acc[g][rg] = __builtin_amdgcn_mfma_f32_16x16x32_bf16(av[rg], bv[g], acc[g][rg], 0, 0, 0);
  }
}

// depth-2 pipelined K-loop over 3 LDS buffers (24.5KB each: A 16K + B 8K).
// Per iter: counted vmcnt(6) (one stage = 6 global_load_lds) -> raw s_barrier
// -> stage(ki+2) -> compute(ki). stage(ki+2) after barrier-ki is WAR-safe.
__device__ __forceinline__ void run_gemm(f32x4 (&acc)[4][2], int nt,
                                         const bf16_t* A0, const bf16_t* A1, int a_switch,
                                         const bf16_t* Bbase, int ldk,
                                         char* smem, int tid, int w, int jj, int rq) {
  auto stage = [&](int ki) {
    char* buf = smem + (ki % 3) * 24576;
    const bf16_t* A = (ki < a_switch) ? A0 : A1;
    int k0 = (ki < a_switch) ? ki * 64 : (ki - a_switch) * 64;
    stage_tileA(A, k0, buf, tid);
    stage_tileB(Bbase, ldk, ki * 64, buf + 16384, tid);
  };
  stage(0);
  stage(1);
#pragma unroll 1
  for (int ki = 0; ki < nt; ++ki) {
    if (ki + 1 < nt) asm volatile("s_waitcnt vmcnt(6)" ::: "memory");
    else             asm volatile("s_waitcnt vmcnt(0)" ::: "memory");
    __builtin_amdgcn_s_barrier();
    if (ki + 2 < nt) stage(ki + 2);
    const char* buf = smem + (ki % 3) * 24576;
    mfma_tile(acc, buf, buf + 16384, w, jj, rq);
  }
}

__device__ void predjob(const Params& p, const bf16_t* h1, int tt, int wg, int w, int l, int tid,
                        float* predbuf) {
  for (int j = w; j < 34; j += 4) {
    int bl = (j >= 17) ? 1 : 0;
    int o = j - bl * 17;
    int b = wg * 2 + bl;
    const bf16_t* hr = h1 + (size_t)b * H_ + l * 16;
    const bf16_t* wr = p.fcW + (size_t)o * H_ + l * 16;
    bf16x8 hv0 = *(const bf16x8*)hr, hv1 = *(const bf16x8*)(hr + 8);
    bf16x8 wv0 = *(const bf16x8*)wr, wv1 = *(const bf16x8*)(wr + 8);
    float acc = 0.f;
#pragma unroll
    for (int e = 0; e < 8; ++e) acc += (float)hv0[e] * (float)wv0[e] + (float)hv1[e] * (float)wv1[e];
#pragma unroll
    for (int d = 32; d > 0; d >>= 1) acc += __shfl_xor(acc, d, 64);
    if (l == 0) predbuf[j] = acc + p.fcb[o];
  }
  __syncthreads();
  if (tid < 2) {
    int b = wg * 2 + tid;
    const float* pr = predbuf + tid * 17;
    float m = pr[0];
    for (int o = 1; o < 16; ++o) m = fmaxf(m, pr[o]);
    float s = 0.f;
    for (int o = 0; o < 16; ++o) s += expf(pr[o] - m);
    float lse = m + logf(s);
    float* dst = p.out + ((size_t)b * T_ + tt) * NOUT;
    for (int o = 0; o < 16; ++o) dst[o] = pr[o] - lse;
    float x = pr[16];
    dst[16] = (x > 0.f) ? -log1pf(expf(-x)) : (x - log1pf(expf(x)));
  }
}

__global__ __launch_bounds__(256, 1) void lstm_main(Params p) {
  __shared__ __align__(16) char smem[3 * 24576];  // 3 pipeline buffers
  __shared__ float predbuf[34];

  const int tid = threadIdx.x;
  const int w = tid >> 6, l = tid & 63;
  const int wg = blockIdx.x;
  const int q = wg >> 3;
  const int mt = q & 3;                       // M-tile 0..3
  const int jt = ((q >> 2) << 3) + (wg & 7);  // j-tile 0..63 (XCD co-located m-tiles)
  const int jj = l & 15;
  const int rq = l >> 4;
  const int jcol = jt * 16 + jj;
  const int npb = jt * 64;

  unsigned phase = 0;

  for (int t = 0; t < T_; ++t) {
    const bf16_t* h0p = (t & 1) ? p.h0b : p.h0a;
    bf16_t*       h0n = (t & 1) ? p.h0a : p.h0b;
    const bf16_t* h1p = (t & 1) ? p.h1b : p.h1a;
    bf16_t*       h1n = (t & 1) ? p.h1a : p.h1b;

    // -------- phase 1: gates0 = h0_prev @ Whh0^T (+ precomputed x-terms) --------
    {
      f32x4 acc[4][2];
#pragma unroll
      for (int g = 0; g < 4; ++g)
#pragma unroll
        for (int rg = 0; rg < 2; ++rg) acc[g][rg] = (f32x4){0.f, 0.f, 0.f, 0.f};

      const bf16_t* Abase = h0p + (size_t)mt * 128 * H_;
      const bf16_t* Bbase = p.PWA + (size_t)jt * 64 * H_;
      run_gemm(acc, 16, Abase, Abase, 16, Bbase, H_, smem, tid, w, jj, rq);

      // epilogue: fused LSTM cell, layer 0
#pragma unroll
      for (int rg = 0; rg < 2; ++rg) {
#pragma unroll
        for (int qq = 0; qq < 4; ++qq) {
          int b = mt * 128 + w * 32 + rg * 16 + rq * 4 + qq;
          int act = 0; float dur = 0.f;
          if (t > 0) {
            act = p.acts[(size_t)b * T_ + t - 1];
            dur = p.durs[(size_t)b * T_ + t - 1];
          }
          float pre[4];
#pragma unroll
          for (int g = 0; g < 4; ++g) {
            int np = npb + g * 16 + jj;
            pre[g] = acc[g][rg][qq] + p.CHp[(size_t)b * NG + np]
                   + p.E16p[(size_t)act * NG + np] + dur * p.wcolp[np];
          }
          float co = p.c0s[(size_t)b * H_ + jcol];
          float cn = sigf(pre[1]) * co + sigf(pre[0]) * tanhf_(pre[2]);
          float hn = sigf(pre[3]) * tanhf_(cn);
          p.c0s[(size_t)b * H_ + jcol] = cn;
          h0n[(size_t)b * H_ + jcol] = (bf16_t)hn;
        }
      }
      if (t > 0) predjob(p, h1p, t - 1, wg, w, l, tid, predbuf);
      ++phase; gbar(p.slots, phase, tid, wg);
    }

    // -------- phase 2: gates1 = [h0_t ; h1_prev] @ [Wih1;Whh1]^T --------
    {
      f32x4 acc[4][2];
#pragma unroll
      for (int g = 0; g < 4; ++g)
#pragma unroll
        for (int rg = 0; rg < 2; ++rg) acc[g][rg] = (f32x4){0.f, 0.f, 0.f, 0.f};

      const bf16_t* A0 = h0n + (size_t)mt * 128 * H_;
      const bf16_t* A1 = h1p + (size_t)mt * 128 * H_;
      const bf16_t* Bbase = p.PWB + (size_t)jt * 64 * 2048;
      run_gemm(acc, 32, A0, A1, 16, Bbase, 2048, smem, tid, w, jj, rq);

      // epilogue: fused LSTM cell, layer 1
#pragma unroll
      for (int rg = 0; rg < 2; ++rg) {
#pragma unroll
        for (int qq = 0; qq < 4; ++qq) {
          int b = mt * 128 + w * 32 + rg * 16 + rq * 4 + qq;
          float pre[4];
#pragma unroll
          for (int g = 0; g < 4; ++g) {
            int np = npb + g * 16 + jj;
            pre[g] = acc[g][rg][qq] + p.biasBp[np];
          }
          float co = p.c1s[(size_t)b * H_ + jcol];
          float cn = sigf(pre[1]) * co + sigf(pre[0]) * tanhf_(pre[2]);
          float hn = sigf(pre[3]) * tanhf_(cn);
          p.c1s[(size_t)b * H_ + jcol] = cn;
          h1n[(size_t)b * H_ + jcol] = (bf16_t)hn;
        }
      }
      ++phase; gbar(p.slots, phase, tid, wg);
    }
  }
  // final prediction for t = T-1 (T even -> last h1 written to h1a)
  predjob(p, (T_ & 1) ? p.h1b : p.h1a, T_ - 1, wg, w, l, tid, predbuf);
}

// ---------------- launch ----------------

extern "C" void kernel_launch(void* const* d_in, const int* in_sizes, int n_in,
                              void* d_out, int out_size, void* d_ws, size_t ws_size,
                              hipStream_t stream) {
  (void)in_sizes; (void)n_in; (void)out_size; (void)ws_size;
  const float* h0   = (const float*)d_in[1];
  const float* c0   = (const float*)d_in[2];
  const float* cond = (const float*)d_in[3];
  const int*   acts = (const int*)d_in[4];
  const float* durs = (const float*)d_in[5];
  const float* emb  = (const float*)d_in[6];
  const float* ffW  = (const float*)d_in[7];
  const float* ffb  = (const float*)d_in[8];
  const float* Wih  = (const float*)d_in[9];
  const float* Whh  = (const float*)d_in[10];
  const float* bih  = (const float*)d_in[11];
  const float* bhh  = (const float*)d_in[12];
  const float* fcW  = (const float*)d_in[13];
  const float* fcb  = (const float*)d_in[14];

  char* ws = (char*)d_ws;
  size_t off = 0;
  auto alloc = [&](size_t bytes) -> char* {
    char* p0 = ws + off;
    off = (off + bytes + 255) & ~(size_t)255;
    return p0;
  };
  unsigned* slots = (unsigned*)alloc(256 * 64);
  bf16_t* PWA     = (bf16_t*)alloc((size_t)NG * H_ * 2);
  bf16_t* PWB     = (bf16_t*)alloc((size_t)NG * 2048 * 2);
  float*  CHp     = (float*)alloc((size_t)B_ * NG * 4);
  float*  E16p    = (float*)alloc((size_t)16 * NG * 4);
  float*  wcolp   = (float*)alloc((size_t)NG * 4);
  float*  biasBp  = (float*)alloc((size_t)NG * 4);
  float*  G       = (float*)alloc((size_t)33 * NG * 4);
  bf16_t* fcWp    = (bf16_t*)alloc((size_t)17 * H_ * 2);
  bf16_t* h0a     = (bf16_t*)alloc((size_t)B_ * H_ * 2);
  bf16_t* h0b     = (bf16_t*)alloc((size_t)B_ * H_ * 2);
  bf16_t* h1a     = (bf16_t*)alloc((size_t)B_ * H_ * 2);
  bf16_t* h1b     = (bf16_t*)alloc((size_t)B_ * H_ * 2);
  float*  c0s     = (float*)alloc((size_t)B_ * H_ * 4);
  float*  c1s     = (float*)alloc((size_t)B_ * H_ * 4);

  hipMemsetAsync(slots, 0, 256 * 64, stream);
  k_pack_wA<<<2048, 256, 0, stream>>>(Whh, PWA);
  k_pack_wB<<<4096, 256, 0, stream>>>(Wih + (size_t)NG * H_, Whh + (size_t)NG * H_, PWB);
  k_G<<<16, 256, 0, stream>>>(Wih, ffW, ffb, G);
  k_CHp<<<8192, 256, 0, stream>>>(cond, G, bih, bhh, CHp);
  k_E16<<<256, 256, 0, stream>>>(emb, Wih, E16p);
  k_misc<<<68, 256, 0, stream>>>(Wih, bih, bhh, fcW, fcWp, biasBp, wcolp);
  k_init<<<2048, 256, 0, stream>>>(h0, c0, h0a, h1a, c0s, c1s);

  Params prm;
  prm.acts = acts; prm.durs = durs;
  prm.PWA = PWA; prm.PWB = PWB;
  prm.CHp = CHp; prm.E16p = E16p; prm.wcolp = wcolp; prm.biasBp = biasBp;
  prm.fcW = fcWp; prm.fcb = fcb;
  prm.h0a = h0a; prm.h0b = h0b; prm.h1a = h1a; prm.h1b = h1b;
  prm.c0s = c0s; prm.c1s = c1s;
  prm.slots = slots; prm.out = (float*)d_out;

  lstm_main<<<dim3(256), dim3(256), 0, stream>>>(prm);
}

// Round 4
// 11207.724 us; speedup vs baseline: 1.0383x; 1.0331x over previous
//
#include <hip/hip_runtime.h>
#include <hip/hip_bf16.h>
#include <stdint.h>

#define B_   512
#define H_   1024
#define T_   144
#define NG   4096
#define NOUT 17

typedef __bf16 bf16_t;
typedef __bf16 bf16x8 __attribute__((ext_vector_type(8)));
typedef float  f32x4  __attribute__((ext_vector_type(4)));

// gate-grouped packed n index: strips of 64 = [j16-group][gate][j&15]
__device__ __host__ __forceinline__ int npack(int n) {
  int g = n >> 10, j = n & 1023;
  return ((j >> 4) << 6) + (g << 4) + (j & 15);
}
__device__ __forceinline__ float sigf(float x) { return 1.f / (1.f + __expf(-x)); }
__device__ __forceinline__ float tanhf_(float x) { return 1.f - 2.f / (__expf(2.f * x) + 1.f); }

// ---------------- prep kernels ----------------
// Weight layouts (elements):  PB[jt][kk][r 0..63][e 0..31]
//   PB1 (K=1024): off = jt*65536  + (k>>5)*2048 + r*32 + (k&31)
//   PB2 (K=2048): off = jt*131072 + (k>>5)*2048 + r*32 + (k&31)
// Packed activations PA[kk][b 0..511][e 0..31]: off = (k>>5)*16384 + b*32 + (k&31)

__global__ void k_pack_wA(const float* __restrict__ Whh0, bf16_t* __restrict__ PB1) {
  int idx = blockIdx.x * 256 + threadIdx.x;     // 4096*128
  int n = idx >> 7, kc = idx & 127;
  const float* s = Whh0 + (size_t)n * H_ + kc * 8;
  bf16x8 v;
#pragma unroll
  for (int e = 0; e < 8; ++e) v[e] = (bf16_t)s[e];
  int np = npack(n), jt = np >> 6, r = np & 63;
  *(bf16x8*)(PB1 + (size_t)jt * 65536 + (kc >> 2) * 2048 + r * 32 + (kc & 3) * 8) = v;
}

__global__ void k_pack_wB(const float* __restrict__ Wih1, const float* __restrict__ Whh1,
                          bf16_t* __restrict__ PB2) {
  int idx = blockIdx.x * 256 + threadIdx.x;     // 4096*256
  int n = idx >> 8, kc = idx & 255;
  int k = kc * 8;
  const float* s = (k < H_) ? (Wih1 + (size_t)n * H_ + k) : (Whh1 + (size_t)n * H_ + (k - H_));
  bf16x8 v;
#pragma unroll
  for (int e = 0; e < 8; ++e) v[e] = (bf16_t)s[e];
  int np = npack(n), jt = np >> 6, r = np & 63;
  *(bf16x8*)(PB2 + (size_t)jt * 131072 + (kc >> 2) * 2048 + r * 32 + (kc & 3) * 8) = v;
}

// G[c][n] = sum_k ff_W[k][c] * Wih0[n][512+k];  G[32][n] = sum_k ff_b[k]*Wih0[n][512+k]
__global__ void k_G(const float* __restrict__ Wih0, const float* __restrict__ ffW,
                    const float* __restrict__ ffb, float* __restrict__ G) {
  int n = blockIdx.x * 256 + threadIdx.x;       // 4096
  float acc[33];
#pragma unroll
  for (int c = 0; c < 33; ++c) acc[c] = 0.f;
  for (int k = 0; k < 512; ++k) {
    float wv = Wih0[(size_t)n * H_ + 512 + k];
    const float* fr = ffW + (size_t)k * 32;
#pragma unroll
    for (int c = 0; c < 32; ++c) acc[c] += wv * fr[c];
    acc[32] += wv * ffb[k];
  }
  for (int c = 0; c < 33; ++c) G[(size_t)c * NG + n] = acc[c];
}

// CHp[b][n'] = biasA[n] + G[32][n] + sum_c cond[b][c]*G[c][n]
__global__ void k_CHp(const float* __restrict__ cond, const float* __restrict__ G,
                      const float* __restrict__ bih0, const float* __restrict__ bhh0,
                      float* __restrict__ CHp) {
  int idx = blockIdx.x * 256 + threadIdx.x;     // 512*4096
  int b = idx >> 12, n = idx & 4095;
  float acc = bih0[n] + bhh0[n] + G[(size_t)32 * NG + n];
  const float* cb = cond + (size_t)b * 32;
#pragma unroll
  for (int c = 0; c < 32; ++c) acc += cb[c] * G[(size_t)c * NG + n];
  CHp[(size_t)b * NG + npack(n)] = acc;
}

// E16p[a][n'] = sum_{k<511} emb[a][k] * Wih0[n][k]
__global__ void k_E16(const float* __restrict__ emb, const float* __restrict__ Wih0,
                      float* __restrict__ E16p) {
  int idx = blockIdx.x * 256 + threadIdx.x;     // 16*4096
  int a = idx & 15, n = idx >> 4;
  const float* er = emb + (size_t)a * 511;
  const float* wr = Wih0 + (size_t)n * H_;
  float acc = 0.f;
  for (int k = 0; k < 511; ++k) acc += er[k] * wr[k];
  E16p[(size_t)a * NG + npack(n)] = acc;
}

__global__ void k_misc(const float* __restrict__ Wih0, const float* __restrict__ bih,
                       const float* __restrict__ bhh, const float* __restrict__ fcW,
                       bf16_t* __restrict__ fcWp, float* __restrict__ biasBp,
                       float* __restrict__ wcolp) {
  int idx = blockIdx.x * 256 + threadIdx.x;     // 17408
  if (idx < NG) {
    int np = npack(idx);
    biasBp[np] = bih[NG + idx] + bhh[NG + idx];
    wcolp[np]  = Wih0[(size_t)idx * H_ + 511];
  }
  if (idx < 17 * H_) fcWp[idx] = (bf16_t)fcW[idx];
}

__global__ void k_init(const float* __restrict__ h0,
                       bf16_t* __restrict__ pah0a, bf16_t* __restrict__ pah1a,
                       bf16_t* __restrict__ h1la) {
  int idx = blockIdx.x * 256 + threadIdx.x;     // 512*128
  int b = idx >> 7, kc = idx & 127;
  const float* s0 = h0 + (size_t)b * H_ + kc * 8;
  const float* s1 = s0 + (size_t)B_ * H_;
  bf16x8 v0, v1;
#pragma unroll
  for (int e = 0; e < 8; ++e) { v0[e] = (bf16_t)s0[e]; v1[e] = (bf16_t)s1[e]; }
  size_t po = (size_t)(kc >> 2) * 16384 + b * 32 + (kc & 3) * 8;
  *(bf16x8*)(pah0a + po) = v0;
  *(bf16x8*)(pah1a + po) = v1;
  *(bf16x8*)(h1la + (size_t)b * H_ + kc * 8) = v1;
}

// ---------------- main persistent kernel ----------------

struct Params {
  const int* acts; const float* durs;
  const bf16_t* PB1; const bf16_t* PB2;
  const float* CHp; const float* E16p; const float* wcolp; const float* biasBp;
  const bf16_t* fcW; const float* fcb;
  const float* c0in;
  bf16_t* pah0a; bf16_t* pah0b; bf16_t* pah1a; bf16_t* pah1b;
  bf16_t* h1la; bf16_t* h1lb;
  unsigned* slots; float* out;
};

// flag-slot grid barrier (proven r2/r3)
__device__ __forceinline__ void gbar(unsigned* slots, unsigned phase, int tid, int wg) {
  __syncthreads();
  if (tid == 0)
    __hip_atomic_store(slots + (size_t)wg * 16, phase, __ATOMIC_RELEASE, __HIP_MEMORY_SCOPE_AGENT);
  while (__hip_atomic_load(slots + (size_t)tid * 16, __ATOMIC_RELAXED, __HIP_MEMORY_SCOPE_AGENT) < phase)
    __builtin_amdgcn_s_sleep(1);
  __builtin_amdgcn_fence(__ATOMIC_ACQUIRE, "agent");
  __syncthreads();
}

struct Frag { bf16x8 a[2]; bf16x8 b[4]; };

template<bool SPLIT>
__device__ __forceinline__ void loadF(Frag& f, int kk, const char* A0, const char* A1,
                                      const char* Bb, int a_off, int b_off) {
  const char* Ab;
  if constexpr (SPLIT) Ab = ((kk < 32) ? (A0 + kk * 32768) : (A1 + (kk - 32) * 32768)) + a_off;
  else                 Ab = A0 + kk * 32768 + a_off;
  f.a[0] = *(const bf16x8*)(Ab);
  f.a[1] = *(const bf16x8*)(Ab + 1024);
  const char* Bp = Bb + kk * 4096 + b_off;
  f.b[0] = *(const bf16x8*)(Bp);
  f.b[1] = *(const bf16x8*)(Bp + 1024);
  f.b[2] = *(const bf16x8*)(Bp + 2048);
  f.b[3] = *(const bf16x8*)(Bp + 3072);
}

__device__ __forceinline__ void mfmaF(f32x4 (&acc)[4][2], const Frag& f) {
#pragma unroll
  for (int g = 0; g < 4; ++g)
#pragma unroll
    for (int rg = 0; rg < 2; ++rg)
      acc[g][rg] = __builtin_amdgcn_mfma_f32_16x16x32_bf16(f.a[rg], f.b[g], acc[g][rg], 0, 0, 0);
}

// barrier-free K-loop: direct global->VGPR fragments, 4 rotating buffers (depth ~2 steps)
template<int NT, bool SPLIT>
__device__ __forceinline__ void kloop(f32x4 (&acc)[4][2], const char* A0, const char* A1,
                                      const char* Bb, int a_off, int b_off) {
  Frag f0, f1, f2, f3;
  loadF<SPLIT>(f0, 0, A0, A1, Bb, a_off, b_off);
  loadF<SPLIT>(f1, 1, A0, A1, Bb, a_off, b_off);
#pragma unroll 1
  for (int kk = 0; kk < NT - 4; kk += 4) {
    loadF<SPLIT>(f2, kk + 2, A0, A1, Bb, a_off, b_off);
    loadF<SPLIT>(f3, kk + 3, A0, A1, Bb, a_off, b_off);
    mfmaF(acc, f0); mfmaF(acc, f1);
    loadF<SPLIT>(f0, kk + 4, A0, A1, Bb, a_off, b_off);
    loadF<SPLIT>(f1, kk + 5, A0, A1, Bb, a_off, b_off);
    mfmaF(acc, f2); mfmaF(acc, f3);
  }
  loadF<SPLIT>(f2, NT - 2, A0, A1, Bb, a_off, b_off);
  loadF<SPLIT>(f3, NT - 1, A0, A1, Bb, a_off, b_off);
  mfmaF(acc, f0); mfmaF(acc, f1); mfmaF(acc, f2); mfmaF(acc, f3);
}

__device__ void predjob(const Params& p, const bf16_t* h1, int tt, int wg, int w, int l, int tid,
                        float* predbuf) {
  for (int j = w; j < 34; j += 4) {
    int bl = (j >= 17) ? 1 : 0;
    int o = j - bl * 17;
    int b = wg * 2 + bl;
    const bf16_t* hr = h1 + (size_t)b * H_ + l * 16;
    const bf16_t* wr = p.fcW + (size_t)o * H_ + l * 16;
    bf16x8 hv0 = *(const bf16x8*)hr, hv1 = *(const bf16x8*)(hr + 8);
    bf16x8 wv0 = *(const bf16x8*)wr, wv1 = *(const bf16x8*)(wr + 8);
    float acc = 0.f;
#pragma unroll
    for (int e = 0; e < 8; ++e) acc += (float)hv0[e] * (float)wv0[e] + (float)hv1[e] * (float)wv1[e];
#pragma unroll
    for (int d = 32; d > 0; d >>= 1) acc += __shfl_xor(acc, d, 64);
    if (l == 0) predbuf[j] = acc + p.fcb[o];
  }
  __syncthreads();
  if (tid < 2) {
    int b = wg * 2 + tid;
    const float* pr = predbuf + tid * 17;
    float m = pr[0];
    for (int o = 1; o < 16; ++o) m = fmaxf(m, pr[o]);
    float s = 0.f;
    for (int o = 0; o < 16; ++o) s += expf(pr[o] - m);
    float lse = m + logf(s);
    float* dst = p.out + ((size_t)b * T_ + tt) * NOUT;
    for (int o = 0; o < 16; ++o) dst[o] = pr[o] - lse;
    float x = pr[16];
    dst[16] = (x > 0.f) ? -log1pf(expf(-x)) : (x - log1pf(expf(x)));
  }
}

__global__ __launch_bounds__(256, 1) void lstm_main(Params p) {
  __shared__ float predbuf[34];

  const int tid = threadIdx.x;
  const int w = tid >> 6, l = tid & 63;
  const int wg = blockIdx.x;
  const int q = wg >> 3;
  const int mt = q & 3;
  const int jt = ((q >> 2) << 3) + (wg & 7);
  const int jj = l & 15, rq = l >> 4;
  const int jcol = jt * 16 + jj;
  const int npb = jt * 64;
  const int a_off = (w * 32 + jj) * 64 + rq * 16;   // byte offset within kk-block
  const int b_off = jj * 64 + rq * 16;
  const char* B1 = (const char*)p.PB1 + (size_t)jt * 131072;
  const char* B2 = (const char*)p.PB2 + (size_t)jt * 262144;
  // packed-h element offset for (b, jcol): he_off + b*32
  const int he_off = (jcol >> 5) * 16384 + (jcol & 31);

  // hoisted per-thread state (t-invariant): CHp, c-state, biases
  float chv[2][4][4], cv0[2][4], cv1[2][4], bzv[4], wcv[4];
#pragma unroll
  for (int rg = 0; rg < 2; ++rg)
#pragma unroll
    for (int qq = 0; qq < 4; ++qq) {
      int b = mt * 128 + w * 32 + rg * 16 + rq * 4 + qq;
      cv0[rg][qq] = p.c0in[(size_t)b * H_ + jcol];
      cv1[rg][qq] = p.c0in[(size_t)B_ * H_ + (size_t)b * H_ + jcol];
#pragma unroll
      for (int g = 0; g < 4; ++g)
        chv[rg][qq][g] = p.CHp[(size_t)b * NG + npb + g * 16 + jj];
    }
#pragma unroll
  for (int g = 0; g < 4; ++g) {
    bzv[g] = p.biasBp[npb + g * 16 + jj];
    wcv[g] = p.wcolp[npb + g * 16 + jj];
  }

  unsigned phase = 0;
#pragma unroll 1
  for (int t = 0; t < T_; ++t) {
    const char* A0p = (const char*)((t & 1) ? p.pah0b : p.pah0a);
    bf16_t*     h0n = (t & 1) ? p.pah0a : p.pah0b;
    const char* A1p = (const char*)((t & 1) ? p.pah1b : p.pah1a);
    bf16_t*     h1n = (t & 1) ? p.pah1a : p.pah1b;
    const bf16_t* h1lp = (t & 1) ? p.h1lb : p.h1la;
    bf16_t*       h1ln = (t & 1) ? p.h1la : p.h1lb;

    // -------- phase 1: gates0 = h0_prev @ Whh0^T (+ precomputed x-terms) --------
    {
      f32x4 acc[4][2];
#pragma unroll
      for (int g = 0; g < 4; ++g)
#pragma unroll
        for (int rg = 0; rg < 2; ++rg) acc[g][rg] = (f32x4){0.f, 0.f, 0.f, 0.f};

      kloop<32, false>(acc, A0p, A0p, B1, a_off, b_off);

#pragma unroll
      for (int rg = 0; rg < 2; ++rg) {
#pragma unroll
        for (int qq = 0; qq < 4; ++qq) {
          int b = mt * 128 + w * 32 + rg * 16 + rq * 4 + qq;
          int act = 0; float dur = 0.f;
          if (t > 0) {
            act = p.acts[(size_t)b * T_ + t - 1];
            dur = p.durs[(size_t)b * T_ + t - 1];
          }
          float pre[4];
#pragma unroll
          for (int g = 0; g < 4; ++g)
            pre[g] = acc[g][rg][qq] + chv[rg][qq][g]
                   + p.E16p[(size_t)act * NG + npb + g * 16 + jj] + dur * wcv[g];
          float cn = sigf(pre[1]) * cv0[rg][qq] + sigf(pre[0]) * tanhf_(pre[2]);
          float hn = sigf(pre[3]) * tanhf_(cn);
          cv0[rg][qq] = cn;
          h0n[(size_t)he_off + b * 32] = (bf16_t)hn;
        }
      }
      if (t > 0) predjob(p, h1lp, t - 1, wg, w, l, tid, predbuf);
      ++phase; gbar(p.slots, phase, tid, wg);
    }

    // -------- phase 2: gates1 = [h0_t ; h1_prev] @ [Wih1;Whh1]^T --------
    {
      f32x4 acc[4][2];
#pragma unroll
      for (int g = 0; g < 4; ++g)
#pragma unroll
        for (int rg = 0; rg < 2; ++rg) acc[g][rg] = (f32x4){0.f, 0.f, 0.f, 0.f};

      kloop<64, true>(acc, (const char*)h0n, A1p, B2, a_off, b_off);

#pragma unroll
      for (int rg = 0; rg < 2; ++rg) {
#pragma unroll
        for (int qq = 0; qq < 4; ++qq) {
          int b = mt * 128 + w * 32 + rg * 16 + rq * 4 + qq;
          float pre[4];
#pragma unroll
          for (int g = 0; g < 4; ++g)
            pre[g] = acc[g][rg][qq] + bzv[g];
          float cn = sigf(pre[1]) * cv1[rg][qq] + sigf(pre[0]) * tanhf_(pre[2]);
          float hn = sigf(pre[3]) * tanhf_(cn);
          cv1[rg][qq] = cn;
          h1n[(size_t)he_off + b * 32] = (bf16_t)hn;
          h1ln[(size_t)b * H_ + jcol] = (bf16_t)hn;
        }
      }
      ++phase; gbar(p.slots, phase, tid, wg);
    }
  }
  // final prediction for t = T-1 (T even -> last h1 linear in h1la)
  predjob(p, (T_ & 1) ? p.h1lb : p.h1la, T_ - 1, wg, w, l, tid, predbuf);
}

// ---------------- launch ----------------

extern "C" void kernel_launch(void* const* d_in, const int* in_sizes, int n_in,
                              void* d_out, int out_size, void* d_ws, size_t ws_size,
                              hipStream_t stream) {
  (void)in_sizes; (void)n_in; (void)out_size; (void)ws_size;
  const float* h0   = (const float*)d_in[1];
  const float* c0   = (const float*)d_in[2];
  const float* cond = (const float*)d_in[3];
  const int*   acts = (const int*)d_in[4];
  const float* durs = (const float*)d_in[5];
  const float* emb  = (const float*)d_in[6];
  const float* ffW  = (const float*)d_in[7];
  const float* ffb  = (const float*)d_in[8];
  const float* Wih  = (const float*)d_in[9];
  const float* Whh  = (const float*)d_in[10];
  const float* bih  = (const float*)d_in[11];
  const float* bhh  = (const float*)d_in[12];
  const float* fcW  = (const float*)d_in[13];
  const float* fcb  = (const float*)d_in[14];

  char* ws = (char*)d_ws;
  size_t off = 0;
  auto alloc = [&](size_t bytes) -> char* {
    char* p0 = ws + off;
    off = (off + bytes + 255) & ~(size_t)255;
    return p0;
  };
  unsigned* slots = (unsigned*)alloc(256 * 64);
  bf16_t* PB1     = (bf16_t*)alloc((size_t)NG * H_ * 2);
  bf16_t* PB2     = (bf16_t*)alloc((size_t)NG * 2048 * 2);
  float*  CHp     = (float*)alloc((size_t)B_ * NG * 4);
  float*  E16p    = (float*)alloc((size_t)16 * NG * 4);
  float*  wcolp   = (float*)alloc((size_t)NG * 4);
  float*  biasBp  = (float*)alloc((size_t)NG * 4);
  float*  G       = (float*)alloc((size_t)33 * NG * 4);
  bf16_t* fcWp    = (bf16_t*)alloc((size_t)17 * H_ * 2);
  bf16_t* pah0a   = (bf16_t*)alloc((size_t)B_ * H_ * 2);
  bf16_t* pah0b   = (bf16_t*)alloc((size_t)B_ * H_ * 2);
  bf16_t* pah1a   = (bf16_t*)alloc((size_t)B_ * H_ * 2);
  bf16_t* pah1b   = (bf16_t*)alloc((size_t)B_ * H_ * 2);
  bf16_t* h1la    = (bf16_t*)alloc((size_t)B_ * H_ * 2);
  bf16_t* h1lb    = (bf16_t*)alloc((size_t)B_ * H_ * 2);

  hipMemsetAsync(slots, 0, 256 * 64, stream);
  k_pack_wA<<<2048, 256, 0, stream>>>(Whh, PB1);
  k_pack_wB<<<4096, 256, 0, stream>>>(Wih + (size_t)NG * H_, Whh + (size_t)NG * H_, PB2);
  k_G<<<16, 256, 0, stream>>>(Wih, ffW, ffb, G);
  k_CHp<<<8192, 256, 0, stream>>>(cond, G, bih, bhh, CHp);
  k_E16<<<256, 256, 0, stream>>>(emb, Wih, E16p);
  k_misc<<<68, 256, 0, stream>>>(Wih, bih, bhh, fcW, fcWp, biasBp, wcolp);
  k_init<<<256, 256, 0, stream>>>(h0, pah0a, pah1a, h1la);

  Params prm;
  prm.acts = acts; prm.durs = durs;
  prm.PB1 = PB1; prm.PB2 = PB2;
  prm.CHp = CHp; prm.E16p = E16p; prm.wcolp = wcolp; prm.biasBp = biasBp;
  prm.fcW = fcWp; prm.fcb = fcb;
  prm.c0in = c0;
  prm.pah0a = pah0a; prm.pah0b = pah0b; prm.pah1a = pah1a; prm.pah1b = pah1b;
  prm.h1la = h1la; prm.h1lb = h1lb;
  prm.slots = slots; prm.out = (float*)d_out;

  lstm_main<<<dim3(256), dim3(256), 0, stream>>>(prm);
}

// Round 5
// 8813.337 us; speedup vs baseline: 1.3204x; 1.2717x over previous
//
#include <hip/hip_runtime.h>
#include <hip/hip_bf16.h>
#include <stdint.h>

#define B_   512
#define H_   1024
#define T_   144
#define NG   4096
#define NOUT 17

typedef __bf16 bf16_t;
typedef __bf16 bf16x8 __attribute__((ext_vector_type(8)));
typedef float  f32x4  __attribute__((ext_vector_type(4)));

// gate-grouped packed n index: strips of 64 = [j16-group][gate][j&15]
__device__ __host__ __forceinline__ int npack(int n) {
  int g = n >> 10, j = n & 1023;
  return ((j >> 4) << 6) + (g << 4) + (j & 15);
}
__device__ __forceinline__ float sigf(float x) { return 1.f / (1.f + __expf(-x)); }
__device__ __forceinline__ float tanhf_(float x) { return 1.f - 2.f / (__expf(2.f * x) + 1.f); }

// ---------------- prep kernels (unchanged from r4) ----------------
// Weight layouts (elements):  PB[jt][kk][r 0..63][e 0..31]
// Packed activations PA[kk][b 0..511][e 0..31]

__global__ void k_pack_wA(const float* __restrict__ Whh0, bf16_t* __restrict__ PB1) {
  int idx = blockIdx.x * 256 + threadIdx.x;     // 4096*128
  int n = idx >> 7, kc = idx & 127;
  const float* s = Whh0 + (size_t)n * H_ + kc * 8;
  bf16x8 v;
#pragma unroll
  for (int e = 0; e < 8; ++e) v[e] = (bf16_t)s[e];
  int np = npack(n), jt = np >> 6, r = np & 63;
  *(bf16x8*)(PB1 + (size_t)jt * 65536 + (kc >> 2) * 2048 + r * 32 + (kc & 3) * 8) = v;
}

__global__ void k_pack_wB(const float* __restrict__ Wih1, const float* __restrict__ Whh1,
                          bf16_t* __restrict__ PB2) {
  int idx = blockIdx.x * 256 + threadIdx.x;     // 4096*256
  int n = idx >> 8, kc = idx & 255;
  int k = kc * 8;
  const float* s = (k < H_) ? (Wih1 + (size_t)n * H_ + k) : (Whh1 + (size_t)n * H_ + (k - H_));
  bf16x8 v;
#pragma unroll
  for (int e = 0; e < 8; ++e) v[e] = (bf16_t)s[e];
  int np = npack(n), jt = np >> 6, r = np & 63;
  *(bf16x8*)(PB2 + (size_t)jt * 131072 + (kc >> 2) * 2048 + r * 32 + (kc & 3) * 8) = v;
}

__global__ void k_G(const float* __restrict__ Wih0, const float* __restrict__ ffW,
                    const float* __restrict__ ffb, float* __restrict__ G) {
  int n = blockIdx.x * 256 + threadIdx.x;       // 4096
  float acc[33];
#pragma unroll
  for (int c = 0; c < 33; ++c) acc[c] = 0.f;
  for (int k = 0; k < 512; ++k) {
    float wv = Wih0[(size_t)n * H_ + 512 + k];
    const float* fr = ffW + (size_t)k * 32;
#pragma unroll
    for (int c = 0; c < 32; ++c) acc[c] += wv * fr[c];
    acc[32] += wv * ffb[k];
  }
  for (int c = 0; c < 33; ++c) G[(size_t)c * NG + n] = acc[c];
}

__global__ void k_CHp(const float* __restrict__ cond, const float* __restrict__ G,
                      const float* __restrict__ bih0, const float* __restrict__ bhh0,
                      float* __restrict__ CHp) {
  int idx = blockIdx.x * 256 + threadIdx.x;     // 512*4096
  int b = idx >> 12, n = idx & 4095;
  float acc = bih0[n] + bhh0[n] + G[(size_t)32 * NG + n];
  const float* cb = cond + (size_t)b * 32;
#pragma unroll
  for (int c = 0; c < 32; ++c) acc += cb[c] * G[(size_t)c * NG + n];
  CHp[(size_t)b * NG + npack(n)] = acc;
}

__global__ void k_E16(const float* __restrict__ emb, const float* __restrict__ Wih0,
                      float* __restrict__ E16p) {
  int idx = blockIdx.x * 256 + threadIdx.x;     // 16*4096
  int a = idx & 15, n = idx >> 4;
  const float* er = emb + (size_t)a * 511;
  const float* wr = Wih0 + (size_t)n * H_;
  float acc = 0.f;
  for (int k = 0; k < 511; ++k) acc += er[k] * wr[k];
  E16p[(size_t)a * NG + npack(n)] = acc;
}

__global__ void k_misc(const float* __restrict__ Wih0, const float* __restrict__ bih,
                       const float* __restrict__ bhh, const float* __restrict__ fcW,
                       bf16_t* __restrict__ fcWp, float* __restrict__ biasBp,
                       float* __restrict__ wcolp) {
  int idx = blockIdx.x * 256 + threadIdx.x;     // 17408
  if (idx < NG) {
    int np = npack(idx);
    biasBp[np] = bih[NG + idx] + bhh[NG + idx];
    wcolp[np]  = Wih0[(size_t)idx * H_ + 511];
  }
  if (idx < 17 * H_) fcWp[idx] = (bf16_t)fcW[idx];
}

__global__ void k_init(const float* __restrict__ h0,
                       bf16_t* __restrict__ pah0a, bf16_t* __restrict__ pah1a) {
  int idx = blockIdx.x * 256 + threadIdx.x;     // 512*128
  int b = idx >> 7, kc = idx & 127;
  const float* s0 = h0 + (size_t)b * H_ + kc * 8;
  const float* s1 = s0 + (size_t)B_ * H_;
  bf16x8 v0, v1;
#pragma unroll
  for (int e = 0; e < 8; ++e) { v0[e] = (bf16_t)s0[e]; v1[e] = (bf16_t)s1[e]; }
  size_t po = (size_t)(kc >> 2) * 16384 + b * 32 + (kc & 3) * 8;
  *(bf16x8*)(pah0a + po) = v0;
  *(bf16x8*)(pah1a + po) = v1;
}

// ---------------- output finalization ----------------

__global__ void k_out(const float* __restrict__ preds, const float* __restrict__ fcb,
                      float* __restrict__ out) {
  int idx = blockIdx.x * 256 + threadIdx.x;     // T*B
  if (idx >= T_ * B_) return;
  int t = idx % T_, b = idx / T_;
  const float* pr = preds + ((size_t)t * B_ + b) * NOUT;
  float v[NOUT];
#pragma unroll
  for (int o = 0; o < NOUT; ++o) v[o] = pr[o] + fcb[o];
  float m = v[0];
#pragma unroll
  for (int o = 1; o < 16; ++o) m = fmaxf(m, v[o]);
  float s = 0.f;
#pragma unroll
  for (int o = 0; o < 16; ++o) s += expf(v[o] - m);
  float lse = m + logf(s);
  float* dst = out + ((size_t)b * T_ + t) * NOUT;
#pragma unroll
  for (int o = 0; o < 16; ++o) dst[o] = v[o] - lse;
  float x = v[16];
  dst[16] = (x > 0.f) ? -log1pf(expf(-x)) : (x - log1pf(expf(x)));
}

// ---------------- main persistent kernel ----------------

struct Params {
  const int* acts; const float* durs;
  const bf16_t* PB1; const bf16_t* PB2;
  const float* CHp; const float* E16p; const float* wcolp; const float* biasBp;
  const bf16_t* fcW;
  const float* c0in;
  bf16_t* pah0a; bf16_t* pah0b; bf16_t* pah1a; bf16_t* pah1b;
  unsigned* slots; float* preds;
};

// Grid barrier WITHOUT acquire fence: release-RMW arrival (flushes dirty L2 to
// the coherence point), SYSTEM-scope (sc0 sc1) poll loads. Cross-XCD-shared
// data (h states) is read with explicit coherent loads instead of invalidating
// L2 — weights stay warm in L2 across all 288 phases.
__device__ __forceinline__ void gbar(unsigned* cnts, unsigned phase, int tid, int wg) {
  __syncthreads();
  if (tid == 0)
    __hip_atomic_fetch_add(cnts + (size_t)(wg & 15) * 64, 1u,
                           __ATOMIC_RELEASE, __HIP_MEMORY_SCOPE_AGENT);
  if (tid < 16) {
    unsigned tgt = phase * 16u;
    const unsigned* a = cnts + (size_t)tid * 64;
    while (__hip_atomic_load(a, __ATOMIC_RELAXED, __HIP_MEMORY_SCOPE_SYSTEM) < tgt)
      __builtin_amdgcn_s_sleep(1);
  }
  __syncthreads();
}

struct Frag { bf16x8 a[2]; bf16x8 b[4]; };

// A (cross-XCD h state): coherence-point loads, bypass stale L2.
// B (read-only packed weights): normal loads, served by warm per-XCD L2.
template<bool SPLIT>
__device__ __forceinline__ void loadF(Frag& f, int kk, const char* A0, const char* A1,
                                      const char* Bb, int a_off, int b_off) {
  const char* Ab;
  if constexpr (SPLIT) Ab = ((kk < 32) ? (A0 + kk * 32768) : (A1 + (kk - 32) * 32768)) + a_off;
  else                 Ab = A0 + kk * 32768 + a_off;
  asm volatile("global_load_dwordx4 %0, %2, off sc0 sc1\n\t"
               "global_load_dwordx4 %1, %2, off offset:1024 sc0 sc1"
               : "=&v"(f.a[0]), "=&v"(f.a[1]) : "v"(Ab));
  const char* Bp = Bb + kk * 4096 + b_off;
  f.b[0] = *(const bf16x8*)(Bp);
  f.b[1] = *(const bf16x8*)(Bp + 1024);
  f.b[2] = *(const bf16x8*)(Bp + 2048);
  f.b[3] = *(const bf16x8*)(Bp + 3072);
}

__device__ __forceinline__ void waitall() {
  asm volatile("s_waitcnt vmcnt(0)" ::: "memory");
  __builtin_amdgcn_sched_barrier(0);   // rule #18: keep MFMA below the wait
}

__device__ __forceinline__ void mfmaF(f32x4 (&acc)[4][2], const Frag& f) {
#pragma unroll
  for (int g = 0; g < 4; ++g)
#pragma unroll
    for (int rg = 0; rg < 2; ++rg)
      acc[g][rg] = __builtin_amdgcn_mfma_f32_16x16x32_bf16(f.a[rg], f.b[g], acc[g][rg], 0, 0, 0);
}

template<int NT, bool SPLIT>
__device__ __forceinline__ void kloop(f32x4 (&acc)[4][2], const char* A0, const char* A1,
                                      const char* Bb, int a_off, int b_off) {
  Frag f0, f1, f2, f3;
  loadF<SPLIT>(f0, 0, A0, A1, Bb, a_off, b_off);
  loadF<SPLIT>(f1, 1, A0, A1, Bb, a_off, b_off);
#pragma unroll 1
  for (int kk = 0; kk < NT - 4; kk += 4) {
    loadF<SPLIT>(f2, kk + 2, A0, A1, Bb, a_off, b_off);
    loadF<SPLIT>(f3, kk + 3, A0, A1, Bb, a_off, b_off);
    waitall();
    mfmaF(acc, f0); mfmaF(acc, f1);
    loadF<SPLIT>(f0, kk + 4, A0, A1, Bb, a_off, b_off);
    loadF<SPLIT>(f1, kk + 5, A0, A1, Bb, a_off, b_off);
    waitall();
    mfmaF(acc, f2); mfmaF(acc, f3);
  }
  loadF<SPLIT>(f2, NT - 2, A0, A1, Bb, a_off, b_off);
  loadF<SPLIT>(f3, NT - 1, A0, A1, Bb, a_off, b_off);
  waitall();
  mfmaF(acc, f0); mfmaF(acc, f1); mfmaF(acc, f2); mfmaF(acc, f3);
}

__global__ __launch_bounds__(256, 1) void lstm_main(Params p) {
  const int tid = threadIdx.x;
  const int w = tid >> 6, l = tid & 63;
  const int wg = blockIdx.x;
  const int q = wg >> 3;
  const int mt = q & 3;
  const int jt = ((q >> 2) << 3) + (wg & 7);
  const int jj = l & 15, rq = l >> 4;
  const int jcol = jt * 16 + jj;
  const int npb = jt * 64;
  const int a_off = (w * 32 + jj) * 64 + rq * 16;
  const int b_off = jj * 64 + rq * 16;
  const char* B1 = (const char*)p.PB1 + (size_t)jt * 131072;
  const char* B2 = (const char*)p.PB2 + (size_t)jt * 262144;
  const int he_off = (jcol >> 5) * 16384 + (jcol & 31);

  // fc-head lane rows: lane jj owns output o=jj over this WG's 16 columns;
  // lane also carries o=16 (dur head) accumulation, committed by jj==15.
  float fcwf[16], fw16f[16];
  {
    const char* fwp = (const char*)p.fcW;
    bf16x8 fa = *(const bf16x8*)(fwp + jj * 2048 + jt * 32);
    bf16x8 fb = *(const bf16x8*)(fwp + jj * 2048 + jt * 32 + 16);
    bf16x8 ga = *(const bf16x8*)(fwp + 16 * 2048 + jt * 32);
    bf16x8 gb = *(const bf16x8*)(fwp + 16 * 2048 + jt * 32 + 16);
#pragma unroll
    for (int e = 0; e < 8; ++e) {
      fcwf[e] = (float)fa[e]; fcwf[8 + e] = (float)fb[e];
      fw16f[e] = (float)ga[e]; fw16f[8 + e] = (float)gb[e];
    }
  }

  // hoisted t-invariant per-thread state
  float chv[2][4][4], cv0[2][4], cv1[2][4], bzv[4], wcv[4];
#pragma unroll
  for (int rg = 0; rg < 2; ++rg)
#pragma unroll
    for (int qq = 0; qq < 4; ++qq) {
      int b = mt * 128 + w * 32 + rg * 16 + rq * 4 + qq;
      cv0[rg][qq] = p.c0in[(size_t)b * H_ + jcol];
      cv1[rg][qq] = p.c0in[(size_t)B_ * H_ + (size_t)b * H_ + jcol];
#pragma unroll
      for (int g = 0; g < 4; ++g)
        chv[rg][qq][g] = p.CHp[(size_t)b * NG + npb + g * 16 + jj];
    }
#pragma unroll
  for (int g = 0; g < 4; ++g) {
    bzv[g] = p.biasBp[npb + g * 16 + jj];
    wcv[g] = p.wcolp[npb + g * 16 + jj];
  }

  unsigned phase = 0;
#pragma unroll 1
  for (int t = 0; t < T_; ++t) {
    const char* A0p = (const char*)((t & 1) ? p.pah0b : p.pah0a);
    bf16_t*     h0n = (t & 1) ? p.pah0a : p.pah0b;
    const char* A1p = (const char*)((t & 1) ? p.pah1b : p.pah1a);
    bf16_t*     h1n = (t & 1) ? p.pah1a : p.pah1b;

    // -------- phase 1: gates0 = h0_prev @ Whh0^T (+ precomputed x-terms) --------
    {
      f32x4 acc[4][2];
#pragma unroll
      for (int g = 0; g < 4; ++g)
#pragma unroll
        for (int rg = 0; rg < 2; ++rg) acc[g][rg] = (f32x4){0.f, 0.f, 0.f, 0.f};

      kloop<32, false>(acc, A0p, A0p, B1, a_off, b_off);

#pragma unroll
      for (int rg = 0; rg < 2; ++rg) {
#pragma unroll
        for (int qq = 0; qq < 4; ++qq) {
          int b = mt * 128 + w * 32 + rg * 16 + rq * 4 + qq;
          int act = 0; float dur = 0.f;
          if (t > 0) {
            act = p.acts[(size_t)b * T_ + t - 1];
            dur = p.durs[(size_t)b * T_ + t - 1];
          }
          float pre[4];
#pragma unroll
          for (int g = 0; g < 4; ++g)
            pre[g] = acc[g][rg][qq] + chv[rg][qq][g]
                   + p.E16p[(size_t)act * NG + npb + g * 16 + jj] + dur * wcv[g];
          float cn = sigf(pre[1]) * cv0[rg][qq] + sigf(pre[0]) * tanhf_(pre[2]);
          float hn = sigf(pre[3]) * tanhf_(cn);
          cv0[rg][qq] = cn;
          h0n[(size_t)he_off + b * 32] = (bf16_t)hn;
        }
      }
      ++phase; gbar(p.slots, phase, tid, wg);
    }

    // -------- phase 2: gates1 = [h0_t ; h1_prev] @ [Wih1;Whh1]^T --------
    {
      f32x4 acc[4][2];
#pragma unroll
      for (int g = 0; g < 4; ++g)
#pragma unroll
        for (int rg = 0; rg < 2; ++rg) acc[g][rg] = (f32x4){0.f, 0.f, 0.f, 0.f};

      kloop<64, true>(acc, (const char*)h0n, A1p, B2, a_off, b_off);

#pragma unroll
      for (int rg = 0; rg < 2; ++rg) {
#pragma unroll
        for (int qq = 0; qq < 4; ++qq) {
          int b = mt * 128 + w * 32 + rg * 16 + rq * 4 + qq;
          float pre[4];
#pragma unroll
          for (int g = 0; g < 4; ++g)
            pre[g] = acc[g][rg][qq] + bzv[g];
          float cn = sigf(pre[1]) * cv1[rg][qq] + sigf(pre[0]) * tanhf_(pre[2]);
          float hn = sigf(pre[3]) * tanhf_(cn);
          cv1[rg][qq] = cn;
          h1n[(size_t)he_off + b * 32] = (bf16_t)hn;

          // fc-head partial: reduce this WG's 16 columns across jj-lanes
          float accO = 0.f, acc16 = 0.f;
#pragma unroll
          for (int s = 0; s < 16; ++s) {
            float hs = __shfl(hn, (l & 48) | s, 64);
            accO  += hs * fcwf[s];
            acc16 += hs * fw16f[s];
          }
          float* pb = p.preds + ((size_t)t * B_ + b) * NOUT;
          atomicAdd(pb + jj, accO);
          if (jj == 15) atomicAdd(pb + 16, acc16);
        }
      }
      ++phase; gbar(p.slots, phase, tid, wg);
    }
  }
}

// ---------------- launch ----------------

extern "C" void kernel_launch(void* const* d_in, const int* in_sizes, int n_in,
                              void* d_out, int out_size, void* d_ws, size_t ws_size,
                              hipStream_t stream) {
  (void)in_sizes; (void)n_in; (void)out_size; (void)ws_size;
  const float* h0   = (const float*)d_in[1];
  const float* c0   = (const float*)d_in[2];
  const float* cond = (const float*)d_in[3];
  const int*   acts = (const int*)d_in[4];
  const float* durs = (const float*)d_in[5];
  const float* emb  = (const float*)d_in[6];
  const float* ffW  = (const float*)d_in[7];
  const float* ffb  = (const float*)d_in[8];
  const float* Wih  = (const float*)d_in[9];
  const float* Whh  = (const float*)d_in[10];
  const float* bih  = (const float*)d_in[11];
  const float* bhh  = (const float*)d_in[12];
  const float* fcW  = (const float*)d_in[13];
  const float* fcb  = (const float*)d_in[14];

  char* ws = (char*)d_ws;
  size_t off = 0;
  auto alloc = [&](size_t bytes) -> char* {
    char* p0 = ws + off;
    off = (off + bytes + 255) & ~(size_t)255;
    return p0;
  };
  unsigned* slots = (unsigned*)alloc(16 * 64 * 4);
  bf16_t* PB1     = (bf16_t*)alloc((size_t)NG * H_ * 2);
  bf16_t* PB2     = (bf16_t*)alloc((size_t)NG * 2048 * 2);
  float*  CHp     = (float*)alloc((size_t)B_ * NG * 4);
  float*  E16p    = (float*)alloc((size_t)16 * NG * 4);
  float*  wcolp   = (float*)alloc((size_t)NG * 4);
  float*  biasBp  = (float*)alloc((size_t)NG * 4);
  float*  G       = (float*)alloc((size_t)33 * NG * 4);
  bf16_t* fcWp    = (bf16_t*)alloc((size_t)17 * H_ * 2);
  bf16_t* pah0a   = (bf16_t*)alloc((size_t)B_ * H_ * 2);
  bf16_t* pah0b   = (bf16_t*)alloc((size_t)B_ * H_ * 2);
  bf16_t* pah1a   = (bf16_t*)alloc((size_t)B_ * H_ * 2);
  bf16_t* pah1b   = (bf16_t*)alloc((size_t)B_ * H_ * 2);
  float*  preds   = (float*)alloc((size_t)T_ * B_ * NOUT * 4);

  hipMemsetAsync(slots, 0, 16 * 64 * 4, stream);
  hipMemsetAsync(preds, 0, (size_t)T_ * B_ * NOUT * 4, stream);
  k_pack_wA<<<2048, 256, 0, stream>>>(Whh, PB1);
  k_pack_wB<<<4096, 256, 0, stream>>>(Wih + (size_t)NG * H_, Whh + (size_t)NG * H_, PB2);
  k_G<<<16, 256, 0, stream>>>(Wih, ffW, ffb, G);
  k_CHp<<<8192, 256, 0, stream>>>(cond, G, bih, bhh, CHp);
  k_E16<<<256, 256, 0, stream>>>(emb, Wih, E16p);
  k_misc<<<68, 256, 0, stream>>>(Wih, bih, bhh, fcW, fcWp, biasBp, wcolp);
  k_init<<<256, 256, 0, stream>>>(h0, pah0a, pah1a);

  Params prm;
  prm.acts = acts; prm.durs = durs;
  prm.PB1 = PB1; prm.PB2 = PB2;
  prm.CHp = CHp; prm.E16p = E16p; prm.wcolp = wcolp; prm.biasBp = biasBp;
  prm.fcW = fcWp;
  prm.c0in = c0;
  prm.pah0a = pah0a; prm.pah0b = pah0b; prm.pah1a = pah1a; prm.pah1b = pah1b;
  prm.slots = slots; prm.preds = preds;

  lstm_main<<<dim3(256), dim3(256), 0, stream>>>(prm);
  k_out<<<(T_ * B_ + 255) / 256, 256, 0, stream>>>(preds, fcb, (float*)d_out);
}

// Round 6
// 7302.498 us; speedup vs baseline: 1.5936x; 1.2069x over previous
//
#include <hip/hip_runtime.h>
#include <hip/hip_bf16.h>
#include <stdint.h>

#define B_   512
#define H_   1024
#define T_   144
#define NG   4096
#define NOUT 17

typedef __bf16 bf16_t;
typedef __bf16 bf16x8 __attribute__((ext_vector_type(8)));
typedef float  f32x4  __attribute__((ext_vector_type(4)));

__device__ __host__ __forceinline__ int npack(int n) {
  int g = n >> 10, j = n & 1023;
  return ((j >> 4) << 6) + (g << 4) + (j & 15);
}
__device__ __forceinline__ float sigf(float x) { return 1.f / (1.f + __expf(-x)); }
__device__ __forceinline__ float tanhf_(float x) { return 1.f - 2.f / (__expf(2.f * x) + 1.f); }

// ---------------- prep kernels (same layouts as r5) ----------------

__global__ void k_pack_wA(const float* __restrict__ Whh0, bf16_t* __restrict__ PB1) {
  int idx = blockIdx.x * 256 + threadIdx.x;     // 4096*128
  int n = idx >> 7, kc = idx & 127;
  const float* s = Whh0 + (size_t)n * H_ + kc * 8;
  bf16x8 v;
#pragma unroll
  for (int e = 0; e < 8; ++e) v[e] = (bf16_t)s[e];
  int np = npack(n), jt = np >> 6, r = np & 63;
  *(bf16x8*)(PB1 + (size_t)jt * 65536 + (kc >> 2) * 2048 + r * 32 + (kc & 3) * 8) = v;
}

__global__ void k_pack_wB(const float* __restrict__ Wih1, const float* __restrict__ Whh1,
                          bf16_t* __restrict__ PB2) {
  int idx = blockIdx.x * 256 + threadIdx.x;     // 4096*256
  int n = idx >> 8, kc = idx & 255;
  int k = kc * 8;
  const float* s = (k < H_) ? (Wih1 + (size_t)n * H_ + k) : (Whh1 + (size_t)n * H_ + (k - H_));
  bf16x8 v;
#pragma unroll
  for (int e = 0; e < 8; ++e) v[e] = (bf16_t)s[e];
  int np = npack(n), jt = np >> 6, r = np & 63;
  *(bf16x8*)(PB2 + (size_t)jt * 131072 + (kc >> 2) * 2048 + r * 32 + (kc & 3) * 8) = v;
}

__global__ void k_G(const float* __restrict__ Wih0, const float* __restrict__ ffW,
                    const float* __restrict__ ffb, float* __restrict__ G) {
  int n = blockIdx.x * 256 + threadIdx.x;       // 4096
  float acc[33];
#pragma unroll
  for (int c = 0; c < 33; ++c) acc[c] = 0.f;
  for (int k = 0; k < 512; ++k) {
    float wv = Wih0[(size_t)n * H_ + 512 + k];
    const float* fr = ffW + (size_t)k * 32;
#pragma unroll
    for (int c = 0; c < 32; ++c) acc[c] += wv * fr[c];
    acc[32] += wv * ffb[k];
  }
  for (int c = 0; c < 33; ++c) G[(size_t)c * NG + n] = acc[c];
}

__global__ void k_CHp(const float* __restrict__ cond, const float* __restrict__ G,
                      const float* __restrict__ bih0, const float* __restrict__ bhh0,
                      float* __restrict__ CHp) {
  int idx = blockIdx.x * 256 + threadIdx.x;     // 512*4096
  int b = idx >> 12, n = idx & 4095;
  float acc = bih0[n] + bhh0[n] + G[(size_t)32 * NG + n];
  const float* cb = cond + (size_t)b * 32;
#pragma unroll
  for (int c = 0; c < 32; ++c) acc += cb[c] * G[(size_t)c * NG + n];
  CHp[(size_t)b * NG + npack(n)] = acc;
}

__global__ void k_E16(const float* __restrict__ emb, const float* __restrict__ Wih0,
                      float* __restrict__ E16p) {
  int idx = blockIdx.x * 256 + threadIdx.x;     // 16*4096
  int a = idx & 15, n = idx >> 4;
  const float* er = emb + (size_t)a * 511;
  const float* wr = Wih0 + (size_t)n * H_;
  float acc = 0.f;
  for (int k = 0; k < 511; ++k) acc += er[k] * wr[k];
  E16p[(size_t)a * NG + npack(n)] = acc;
}

__global__ void k_misc(const float* __restrict__ Wih0, const float* __restrict__ bih,
                       const float* __restrict__ bhh, const float* __restrict__ fcW,
                       bf16_t* __restrict__ fcWp, float* __restrict__ biasBp,
                       float* __restrict__ wcolp) {
  int idx = blockIdx.x * 256 + threadIdx.x;     // 17408
  if (idx < NG) {
    int np = npack(idx);
    biasBp[np] = bih[NG + idx] + bhh[NG + idx];
    wcolp[np]  = Wih0[(size_t)idx * H_ + 511];
  }
  if (idx < 17 * H_) fcWp[idx] = (bf16_t)fcW[idx];
}

__global__ void k_init(const float* __restrict__ h0,
                       bf16_t* __restrict__ pah0i, bf16_t* __restrict__ pah1a) {
  int idx = blockIdx.x * 256 + threadIdx.x;     // 512*128
  int b = idx >> 7, kc = idx & 127;
  const float* s0 = h0 + (size_t)b * H_ + kc * 8;
  const float* s1 = s0 + (size_t)B_ * H_;
  bf16x8 v0, v1;
#pragma unroll
  for (int e = 0; e < 8; ++e) { v0[e] = (bf16_t)s0[e]; v1[e] = (bf16_t)s1[e]; }
  size_t po = (size_t)(kc >> 2) * 16384 + b * 32 + (kc & 3) * 8;
  *(bf16x8*)(pah0i + po) = v0;
  *(bf16x8*)(pah1a + po) = v1;
}

// ---------------- output finalization ----------------

__global__ void k_out(const float* __restrict__ preds, const float* __restrict__ fcb,
                      float* __restrict__ out) {
  int idx = blockIdx.x * 256 + threadIdx.x;     // T*B
  if (idx >= T_ * B_) return;
  int t = idx % T_, b = idx / T_;
  const float* pr = preds + ((size_t)t * B_ + b) * NOUT;
  float v[NOUT];
#pragma unroll
  for (int o = 0; o < NOUT; ++o) v[o] = pr[o] + fcb[o];
  float m = v[0];
#pragma unroll
  for (int o = 1; o < 16; ++o) m = fmaxf(m, v[o]);
  float s = 0.f;
#pragma unroll
  for (int o = 0; o < 16; ++o) s += expf(v[o] - m);
  float lse = m + logf(s);
  float* dst = out + ((size_t)b * T_ + t) * NOUT;
#pragma unroll
  for (int o = 0; o < 16; ++o) dst[o] = v[o] - lse;
  float x = v[16];
  dst[16] = (x > 0.f) ? -log1pf(expf(-x)) : (x - log1pf(expf(x)));
}

// ---------------- main persistent kernel ----------------

struct Params {
  const int* acts; const float* durs;
  const bf16_t* PB1; const bf16_t* PB2;
  const float* CHp; const float* E16p; const float* wcolp; const float* biasBp;
  const bf16_t* fcW;
  const float* c0in;
  const bf16_t* pah0i;
  bf16_t* pah0a; bf16_t* pah0b; bf16_t* pah1a; bf16_t* pah1b;
  unsigned* slots; float* preds;
};

// Grid barrier: per-WG store-release slot (no RMW contention; release at agent
// scope write-backs dirty L2 -> LLC, r5-proven), SYSTEM-scope polls (bypass
// stale per-XCD L2). No acquire fence -> weights stay warm in L2 forever.
__device__ __forceinline__ void gbar(unsigned* slots, unsigned phase, int tid, int wg) {
  __syncthreads();   // compiler drains vmcnt(0): all epilogue stores in L2
  if (tid == 0) {
    __builtin_amdgcn_fence(__ATOMIC_RELEASE, "agent");
    __hip_atomic_store(slots + (size_t)wg * 16, phase, __ATOMIC_RELAXED, __HIP_MEMORY_SCOPE_AGENT);
  }
  if (tid < 64) {
#pragma unroll 1
    for (int j = 0; j < 4; ++j) {
      const unsigned* a = slots + (size_t)(tid + j * 64) * 16;
      while (__hip_atomic_load(a, __ATOMIC_RELAXED, __HIP_MEMORY_SCOPE_SYSTEM) < phase)
        __builtin_amdgcn_s_sleep(1);
    }
  }
  __syncthreads();
}

// merged-block slot: h0-frag (a), h1-frag (e), W0 (b), W1ih (c), W1hh (d)
struct Slot { bf16x8 a0, a1, e0, e1, b0, b1, b2, b3, c0, c1, c2, c3, d0, d1, d2, d3; };

__device__ __forceinline__ void ldA(bf16x8& r0, bf16x8& r1, const char* p) {
  asm volatile("global_load_dwordx4 %0, %2, off sc0 sc1\n\t"
               "global_load_dwordx4 %1, %2, off offset:1024 sc0 sc1"
               : "=&v"(r0), "=&v"(r1) : "v"(p));
}
__device__ __forceinline__ void ldApl(bf16x8& r0, bf16x8& r1, const char* p) {
  asm volatile("global_load_dwordx4 %0, %2, off\n\t"
               "global_load_dwordx4 %1, %2, off offset:1024"
               : "=&v"(r0), "=&v"(r1) : "v"(p));
}
__device__ __forceinline__ void ldB4(bf16x8& r0, bf16x8& r1, bf16x8& r2, bf16x8& r3,
                                     const char* p) {
  asm volatile("global_load_dwordx4 %0, %4, off\n\t"
               "global_load_dwordx4 %1, %4, off offset:1024\n\t"
               "global_load_dwordx4 %2, %4, off offset:2048\n\t"
               "global_load_dwordx4 %3, %4, off offset:3072"
               : "=&v"(r0), "=&v"(r1), "=&v"(r2), "=&v"(r3) : "v"(p));
}

#define VMW(N) { asm volatile("s_waitcnt vmcnt(" #N ")" ::: "memory"); \
                 __builtin_amdgcn_sched_barrier(0); }

#define MFM(ACC, AV, BV) ACC = __builtin_amdgcn_mfma_f32_16x16x32_bf16(AV, BV, ACC, 0, 0, 0)

__device__ __forceinline__ void compS(f32x4 (&A0)[4][2], f32x4 (&A1)[4][2], const Slot& S) {
  MFM(A0[0][0], S.a0, S.b0); MFM(A0[0][1], S.a1, S.b0);
  MFM(A0[1][0], S.a0, S.b1); MFM(A0[1][1], S.a1, S.b1);
  MFM(A0[2][0], S.a0, S.b2); MFM(A0[2][1], S.a1, S.b2);
  MFM(A0[3][0], S.a0, S.b3); MFM(A0[3][1], S.a1, S.b3);
  MFM(A1[0][0], S.a0, S.c0); MFM(A1[0][1], S.a1, S.c0);
  MFM(A1[1][0], S.a0, S.c1); MFM(A1[1][1], S.a1, S.c1);
  MFM(A1[2][0], S.a0, S.c2); MFM(A1[2][1], S.a1, S.c2);
  MFM(A1[3][0], S.a0, S.c3); MFM(A1[3][1], S.a1, S.c3);
  MFM(A1[0][0], S.e0, S.d0); MFM(A1[0][1], S.e1, S.d0);
  MFM(A1[1][0], S.e0, S.d1); MFM(A1[1][1], S.e1, S.d1);
  MFM(A1[2][0], S.e0, S.d2); MFM(A1[2][1], S.e1, S.d2);
  MFM(A1[3][0], S.e0, S.d3); MFM(A1[3][1], S.e1, S.d3);
}

__device__ __forceinline__ void compP(f32x4 (&A0)[4][2], const Slot& S) {
  MFM(A0[0][0], S.a0, S.b0); MFM(A0[0][1], S.a1, S.b0);
  MFM(A0[1][0], S.a0, S.b1); MFM(A0[1][1], S.a1, S.b1);
  MFM(A0[2][0], S.a0, S.b2); MFM(A0[2][1], S.a1, S.b2);
  MFM(A0[3][0], S.a0, S.b3); MFM(A0[3][1], S.a1, S.b3);
}

__global__ __launch_bounds__(256, 1) void lstm_main(Params p) {
  const int tid = threadIdx.x;
  const int w = tid >> 6, l = tid & 63;
  const int wg = blockIdx.x;
  const int q = wg >> 3;
  const int mt = q & 3;
  const int jt = ((q >> 2) << 3) + (wg & 7);
  const int jj = l & 15, rq = l >> 4;
  const int jcol = jt * 16 + jj;
  const int npb = jt * 64;
  const int a_off = (w * 32 + jj) * 64 + rq * 16;
  const int b_off = jj * 64 + rq * 16;
  const char* Bw0 = (const char*)p.PB1 + (size_t)jt * 131072;
  const char* Bw1 = (const char*)p.PB2 + (size_t)jt * 262144;
  const int he_off = (jcol >> 5) * 16384 + (jcol & 31);

  // fc-head rows (lane jj owns output o=jj; all lanes carry o=16 partial)
  float fcwf[16], fw16f[16];
  {
    const char* fwp = (const char*)p.fcW;
    bf16x8 fa = *(const bf16x8*)(fwp + jj * 2048 + jt * 32);
    bf16x8 fb = *(const bf16x8*)(fwp + jj * 2048 + jt * 32 + 16);
    bf16x8 ga = *(const bf16x8*)(fwp + 16 * 2048 + jt * 32);
    bf16x8 gb = *(const bf16x8*)(fwp + 16 * 2048 + jt * 32 + 16);
#pragma unroll
    for (int e = 0; e < 8; ++e) {
      fcwf[e] = (float)fa[e]; fcwf[8 + e] = (float)fb[e];
      fw16f[e] = (float)ga[e]; fw16f[8 + e] = (float)gb[e];
    }
  }

  // hoisted t-invariant per-thread state
  float chv[2][4][4], cv0[2][4], cv1[2][4], bzv[4], wcv[4];
#pragma unroll
  for (int rg = 0; rg < 2; ++rg)
#pragma unroll
    for (int qq = 0; qq < 4; ++qq) {
      int b = mt * 128 + w * 32 + rg * 16 + rq * 4 + qq;
      cv0[rg][qq] = p.c0in[(size_t)b * H_ + jcol];
      cv1[rg][qq] = p.c0in[(size_t)B_ * H_ + (size_t)b * H_ + jcol];
#pragma unroll
      for (int g = 0; g < 4; ++g)
        chv[rg][qq][g] = p.CHp[(size_t)b * NG + npb + g * 16 + jj];
    }
#pragma unroll
  for (int g = 0; g < 4; ++g) {
    bzv[g] = p.biasBp[npb + g * 16 + jj];
    wcv[g] = p.wcolp[npb + g * 16 + jj];
  }

  Slot S0, S1, S2;

  // ======== prologue: h0^(0) = cell0(x_0, h0_init) — GEMM vs W0 only ========
  {
    f32x4 acc0[4][2];
#pragma unroll
    for (int g = 0; g < 4; ++g)
#pragma unroll
      for (int rg = 0; rg < 2; ++rg) acc0[g][rg] = (f32x4){0.f, 0.f, 0.f, 0.f};

    const char* Ai = (const char*)p.pah0i;
    auto Pp = [&](int kk, Slot& S) {
      ldApl(S.a0, S.a1, Ai + (size_t)kk * 32768 + a_off);
      ldB4(S.b0, S.b1, S.b2, S.b3, Bw0 + (size_t)kk * 4096 + b_off);
    };
    Pp(0, S0); Pp(1, S1);
#pragma unroll 1
    for (int o = 0; o < 10; ++o) {
      const int k = o * 3;
      Pp(k + 2, S2); VMW(12); compP(acc0, S0);
      Pp(k + 3, S0); VMW(12); compP(acc0, S1);
      Pp(k + 4, S1); VMW(12); compP(acc0, S2);
    }
    VMW(6);  compP(acc0, S0);
    VMW(0);  compP(acc0, S1);

    bf16_t* H0n = p.pah0a;
#pragma unroll
    for (int rg = 0; rg < 2; ++rg)
#pragma unroll
      for (int qq = 0; qq < 4; ++qq) {
        int b = mt * 128 + w * 32 + rg * 16 + rq * 4 + qq;
        float pre[4];
#pragma unroll
        for (int g = 0; g < 4; ++g)
          pre[g] = acc0[g][rg][qq] + chv[rg][qq][g] + p.E16p[npb + g * 16 + jj];
        float cn = sigf(pre[1]) * cv0[rg][qq] + sigf(pre[0]) * tanhf_(pre[2]);
        float hn = sigf(pre[3]) * tanhf_(cn);
        cv0[rg][qq] = cn;
        H0n[(size_t)he_off + b * 32] = (bf16_t)hn;
      }
    gbar(p.slots, 1u, tid, wg);
  }

  // ======== main: superstep s computes h1^(s) AND h0^(s+1), one barrier ========
#pragma unroll 1
  for (int s = 0; s < T_; ++s) {
    const char* Ah0 = (const char*)((s & 1) ? p.pah0b : p.pah0a);
    bf16_t*     H0n = (s & 1) ? p.pah0a : p.pah0b;
    const char* Ah1 = (const char*)((s & 1) ? p.pah1b : p.pah1a);
    bf16_t*     H1n = (s & 1) ? p.pah1a : p.pah1b;

    f32x4 acc0[4][2], acc1[4][2];
#pragma unroll
    for (int g = 0; g < 4; ++g)
#pragma unroll
      for (int rg = 0; rg < 2; ++rg) {
        acc0[g][rg] = (f32x4){0.f, 0.f, 0.f, 0.f};
        acc1[g][rg] = (f32x4){0.f, 0.f, 0.f, 0.f};
      }

    auto Pm = [&](int kk, Slot& S) {
      ldA(S.a0, S.a1, Ah0 + (size_t)kk * 32768 + a_off);
      ldA(S.e0, S.e1, Ah1 + (size_t)kk * 32768 + a_off);
      ldB4(S.b0, S.b1, S.b2, S.b3, Bw0 + (size_t)kk * 4096 + b_off);
      ldB4(S.c0, S.c1, S.c2, S.c3, Bw1 + (size_t)kk * 4096 + b_off);
      ldB4(S.d0, S.d1, S.d2, S.d3, Bw1 + (size_t)(32 + kk) * 4096 + b_off);
    };
    Pm(0, S0); Pm(1, S1);
#pragma unroll 1
    for (int o = 0; o < 10; ++o) {
      const int k = o * 3;
      Pm(k + 2, S2); VMW(32); compS(acc0, acc1, S0);
      Pm(k + 3, S0); VMW(32); compS(acc0, acc1, S1);
      Pm(k + 4, S1); VMW(32); compS(acc0, acc1, S2);
    }
    VMW(16); compS(acc0, acc1, S0);
    VMW(0);  compS(acc0, acc1, S1);

    // epilogue: cell1 -> h1^(s) + fc head;  cell0 -> h0^(s+1)
#pragma unroll
    for (int rg = 0; rg < 2; ++rg)
#pragma unroll
      for (int qq = 0; qq < 4; ++qq) {
        int b = mt * 128 + w * 32 + rg * 16 + rq * 4 + qq;
        // ---- layer 1 cell ----
        float pre1[4];
#pragma unroll
        for (int g = 0; g < 4; ++g) pre1[g] = acc1[g][rg][qq] + bzv[g];
        float cn1 = sigf(pre1[1]) * cv1[rg][qq] + sigf(pre1[0]) * tanhf_(pre1[2]);
        float hn1 = sigf(pre1[3]) * tanhf_(cn1);
        cv1[rg][qq] = cn1;
        H1n[(size_t)he_off + b * 32] = (bf16_t)hn1;
        // fc-head partials over this WG's 16 columns
        float accO = 0.f, acc16 = 0.f;
#pragma unroll
        for (int sc = 0; sc < 16; ++sc) {
          float hs = __shfl(hn1, (l & 48) | sc, 64);
          accO  += hs * fcwf[sc];
          acc16 += hs * fw16f[sc];
        }
        float* pb = p.preds + ((size_t)s * B_ + b) * NOUT;
        atomicAdd(pb + jj, accO);
        if (jj == 15) atomicAdd(pb + 16, acc16);
        // ---- layer 0 cell (next step's h0) ----
        int act = p.acts[(size_t)b * T_ + s];
        float dur = p.durs[(size_t)b * T_ + s];
        float pre0[4];
#pragma unroll
        for (int g = 0; g < 4; ++g)
          pre0[g] = acc0[g][rg][qq] + chv[rg][qq][g]
                  + p.E16p[(size_t)act * NG + npb + g * 16 + jj] + dur * wcv[g];
        float cn0 = sigf(pre0[1]) * cv0[rg][qq] + sigf(pre0[0]) * tanhf_(pre0[2]);
        float hn0 = sigf(pre0[3]) * tanhf_(cn0);
        cv0[rg][qq] = cn0;
        H0n[(size_t)he_off + b * 32] = (bf16_t)hn0;
      }
    gbar(p.slots, (unsigned)(s + 2), tid, wg);
  }
}

// ---------------- launch ----------------

extern "C" void kernel_launch(void* const* d_in, const int* in_sizes, int n_in,
                              void* d_out, int out_size, void* d_ws, size_t ws_size,
                              hipStream_t stream) {
  (void)in_sizes; (void)n_in; (void)out_size; (void)ws_size;
  const float* h0   = (const float*)d_in[1];
  const float* c0   = (const float*)d_in[2];
  const float* cond = (const float*)d_in[3];
  const int*   acts = (const int*)d_in[4];
  const float* durs = (const float*)d_in[5];
  const float* emb  = (const float*)d_in[6];
  const float* ffW  = (const float*)d_in[7];
  const float* ffb  = (const float*)d_in[8];
  const float* Wih  = (const float*)d_in[9];
  const float* Whh  = (const float*)d_in[10];
  const float* bih  = (const float*)d_in[11];
  const float* bhh  = (const float*)d_in[12];
  const float* fcW  = (const float*)d_in[13];
  const float* fcb  = (const float*)d_in[14];

  char* ws = (char*)d_ws;
  size_t off = 0;
  auto alloc = [&](size_t bytes) -> char* {
    char* p0 = ws + off;
    off = (off + bytes + 255) & ~(size_t)255;
    return p0;
  };
  unsigned* slots = (unsigned*)alloc(256 * 64);
  bf16_t* PB1     = (bf16_t*)alloc((size_t)NG * H_ * 2);
  bf16_t* PB2     = (bf16_t*)alloc((size_t)NG * 2048 * 2);
  float*  CHp     = (float*)alloc((size_t)B_ * NG * 4);
  float*  E16p    = (float*)alloc((size_t)16 * NG * 4);
  float*  wcolp   = (float*)alloc((size_t)NG * 4);
  float*  biasBp  = (float*)alloc((size_t)NG * 4);
  float*  G       = (float*)alloc((size_t)33 * NG * 4);
  bf16_t* fcWp    = (bf16_t*)alloc((size_t)17 * H_ * 2);
  bf16_t* pah0i   = (bf16_t*)alloc((size_t)B_ * H_ * 2);
  bf16_t* pah0a   = (bf16_t*)alloc((size_t)B_ * H_ * 2);
  bf16_t* pah0b   = (bf16_t*)alloc((size_t)B_ * H_ * 2);
  bf16_t* pah1a   = (bf16_t*)alloc((size_t)B_ * H_ * 2);
  bf16_t* pah1b   = (bf16_t*)alloc((size_t)B_ * H_ * 2);
  float*  preds   = (float*)alloc((size_t)T_ * B_ * NOUT * 4);

  hipMemsetAsync(slots, 0, 256 * 64, stream);
  hipMemsetAsync(preds, 0, (size_t)T_ * B_ * NOUT * 4, stream);
  k_pack_wA<<<2048, 256, 0, stream>>>(Whh, PB1);
  k_pack_wB<<<4096, 256, 0, stream>>>(Wih + (size_t)NG * H_, Whh + (size_t)NG * H_, PB2);
  k_G<<<16, 256, 0, stream>>>(Wih, ffW, ffb, G);
  k_CHp<<<8192, 256, 0, stream>>>(cond, G, bih, bhh, CHp);
  k_E16<<<256, 256, 0, stream>>>(emb, Wih, E16p);
  k_misc<<<68, 256, 0, stream>>>(Wih, bih, bhh, fcW, fcWp, biasBp, wcolp);
  k_init<<<256, 256, 0, stream>>>(h0, pah0i, pah1a);

  Params prm;
  prm.acts = acts; prm.durs = durs;
  prm.PB1 = PB1; prm.PB2 = PB2;
  prm.CHp = CHp; prm.E16p = E16p; prm.wcolp = wcolp; prm.biasBp = biasBp;
  prm.fcW = fcWp;
  prm.c0in = c0;
  prm.pah0i = pah0i;
  prm.pah0a = pah0a; prm.pah0b = pah0b; prm.pah1a = pah1a; prm.pah1b = pah1b;
  prm.slots = slots; prm.preds = preds;

  lstm_main<<<dim3(256), dim3(256), 0, stream>>>(prm);
  k_out<<<(T_ * B_ + 255) / 256, 256, 0, stream>>>(preds, fcb, (float*)d_out);
}